// Round 3
// baseline (4506.651 us; speedup 1.0000x reference)
//
#include <hip/hip_runtime.h>

// ---------------- problem constants ----------------
constexpr int kB   = 128;   // batch
constexpr int kSin = 50;    // encoder seq len
constexpr int kT   = 25;    // decoder steps
constexpr int kD   = 128;   // feature dim (IN_SIZE == OUT_SIZE)
constexpr int kR   = 2048;  // RNN hidden
constexpr int kNB  = 256;   // grid blocks (1 per CU)
constexpr int kNT  = 256;   // threads per block

typedef __bf16 bf16x8 __attribute__((ext_vector_type(8)));
typedef float  f32x4  __attribute__((ext_vector_type(4)));
typedef unsigned short u16;
typedef unsigned short u16x4v __attribute__((ext_vector_type(4)));

__device__ __forceinline__ float bf2f(u16 u) {
    union { unsigned i; float f; } x; x.i = ((unsigned)u) << 16; return x.f;
}
__device__ __forceinline__ u16 f2bf(float f) {
    union { float f; unsigned i; } x; x.f = f;
    return (u16)((x.i + 0x7FFFu + ((x.i >> 16) & 1u)) >> 16);
}
__device__ __forceinline__ float sigmoidf(float x) { return 1.f / (1.f + __expf(-x)); }

// ---------------- grid barrier (non-cooperative, flag-scan) ----------------
__device__ __forceinline__ void gbar(unsigned* flags, unsigned* gen, unsigned k)
{
    __syncthreads();
    if (threadIdx.x == 0)
        __hip_atomic_store(&flags[blockIdx.x], k, __ATOMIC_RELEASE, __HIP_MEMORY_SCOPE_AGENT);
    if (blockIdx.x == 0 && threadIdx.x < 64) {
        const int i0 = (int)threadIdx.x * 4;
        for (;;) {
            unsigned a = __hip_atomic_load(&flags[i0 + 0], __ATOMIC_RELAXED, __HIP_MEMORY_SCOPE_AGENT);
            unsigned b = __hip_atomic_load(&flags[i0 + 1], __ATOMIC_RELAXED, __HIP_MEMORY_SCOPE_AGENT);
            unsigned c = __hip_atomic_load(&flags[i0 + 2], __ATOMIC_RELAXED, __HIP_MEMORY_SCOPE_AGENT);
            unsigned d = __hip_atomic_load(&flags[i0 + 3], __ATOMIC_RELAXED, __HIP_MEMORY_SCOPE_AGENT);
            if (__ballot((a == k) && (b == k) && (c == k) && (d == k)) == ~0ull) break;
            __builtin_amdgcn_s_sleep(1);
        }
        __builtin_amdgcn_fence(__ATOMIC_ACQUIRE, "agent");
        if (threadIdx.x == 0)
            __hip_atomic_store(gen, k, __ATOMIC_RELEASE, __HIP_MEMORY_SCOPE_AGENT);
    }
    if (threadIdx.x == 0) {
        while (__hip_atomic_load(gen, __ATOMIC_RELAXED, __HIP_MEMORY_SCOPE_AGENT) != k)
            __builtin_amdgcn_s_sleep(1);
        __builtin_amdgcn_fence(__ATOMIC_ACQUIRE, "agent");
    }
    __syncthreads();
}

// ---------------- f32 -> bf16 array conversion (phase 0) ----------------
__device__ __forceinline__ void cvt_f32_bf16(const float* __restrict__ s, u16* __restrict__ d,
                                             int n4, int gtid, int gstride)
{
    for (int i = gtid; i < n4; i += gstride) {
        float4 v = ((const float4*)s)[i];
        u16x4v o = { f2bf(v.x), f2bf(v.y), f2bf(v.z), f2bf(v.w) };
        ((u16x4v*)d)[i] = o;
    }
}

// ---------------- 64-row MFMA tile GEMM ----------------
// C[64 x NT*16] += A[64 x K] * B^T; B rows (= output cols) for n-tile j, lane n
// are Bw[nbase0 + j*nstride + n][k].  BK=64, LDS-staged, +8 pad (stride 72).
template<int NT>
__device__ __forceinline__ void mma_rows64(
    const u16* __restrict__ A, int lda,
    const u16* __restrict__ Bw, int ldb,
    int K, int nbase0, int nstride,
    f32x4 (&acc)[NT],
    u16* sA, u16* sB)
{
    const int tid  = threadIdx.x;
    const int lane = tid & 63, wv = tid >> 6;
    const int ar   = lane & 15, aq = lane >> 4;
    for (int k0 = 0; k0 < K; k0 += 64) {
        __syncthreads();
        {   // stage A: 64 rows x 64 cols (bf16)
            int row = tid >> 3, cc = tid & 7;
            *(uint4*)&sA[row * 72 + cc * 8]        = *(const uint4*)&A[row * lda + k0 + cc * 8];
            *(uint4*)&sA[(row + 32) * 72 + cc * 8] = *(const uint4*)&A[(row + 32) * lda + k0 + cc * 8];
        }
        for (int chunk = tid; chunk < NT * 128; chunk += kNT) {  // stage B: NT*16 rows x 64
            int r = chunk >> 3, cc = chunk & 7;
            int j = r >> 4, n = r & 15;
            *(uint4*)&sB[r * 72 + cc * 8] =
                *(const uint4*)&Bw[(size_t)(nbase0 + j * nstride + n) * ldb + k0 + cc * 8];
        }
        __syncthreads();
#pragma unroll
        for (int kk = 0; kk < 64; kk += 32) {
            bf16x8 a0 = *(const bf16x8*)&sA[(wv * 16 + ar) * 72 + kk + aq * 8];
#pragma unroll
            for (int j = 0; j < NT; ++j) {
                bf16x8 b = *(const bf16x8*)&sB[(j * 16 + ar) * 72 + kk + aq * 8];
                acc[j] = __builtin_amdgcn_mfma_f32_16x16x32_bf16(a0, b, acc[j], 0, 0, 0);
            }
        }
    }
}

// ---------------- one GRU step (this block's 64 rows x 16 h-cols) ----------------
// bias_f32 layout: [b_ih 6144 | b_hh 6144 | fc1_b 128 | fc2_b 128]
__device__ __forceinline__ void gru_step(
    const u16* __restrict__ xb, int mrow0, int wgc,
    const u16* __restrict__ w_ih, const u16* __restrict__ w_hh,
    const float* __restrict__ bias_f32,
    const u16* __restrict__ hb_cur, u16* __restrict__ hb_nxt,
    u16* sA, u16* sB)
{
    const int tid = threadIdx.x;
    const int lane = tid & 63, wv = tid >> 6, ar = lane & 15, aq = lane >> 4;
    const f32x4 zz = {0.f, 0.f, 0.f, 0.f};
    f32x4 ah[3] = {zz, zz, zz};   // h-side gates (r, z, n)
    f32x4 ai[3] = {zz, zz, zz};   // x-side gates (r, z, n)
    mma_rows64<3>(hb_cur + mrow0 * kR, kR, w_hh, kR, kR, wgc * 16, kR, ah, sA, sB);
    mma_rows64<3>(xb + mrow0 * kD, kD, w_ih, kD, kD, wgc * 16, kR, ai, sA, sB);

    const int hc = wgc * 16 + ar;
    const float brz = bias_f32[hc]            + bias_f32[3 * kR + hc];
    const float bzz = bias_f32[kR + hc]       + bias_f32[4 * kR + hc];
    const float bin = bias_f32[2 * kR + hc];
    const float bhn = bias_f32[5 * kR + hc];
#pragma unroll
    for (int r = 0; r < 4; ++r) {
        const int m = mrow0 + wv * 16 + aq * 4 + r;   // C/D: row=(lane>>4)*4+reg, col=lane&15
        float rg = sigmoidf(ah[0][r] + ai[0][r] + brz);
        float zg = sigmoidf(ah[1][r] + ai[1][r] + bzz);
        float ng = tanhf(ai[2][r] + bin + rg * (ah[2][r] + bhn));
        float hp = bf2f(hb_cur[(size_t)m * kR + hc]);
        float hn = (1.f - zg) * ng + zg * hp;
        hb_nxt[(size_t)m * kR + hc] = f2bf(hn);
    }
}

// ---------------- the whole model, one persistent kernel ----------------
__global__ __launch_bounds__(kNT, 1) void seq2seq_kernel(
    const void* __restrict__ enc_in_raw,   // [128][50][128]  f32 or bf16 (auto-detected)
    const void* __restrict__ fc1_w_raw,    // [128][128]
    const void* __restrict__ fc1_b_raw,    // [128]
    const void* __restrict__ w_ih_raw,     // [6144][128]
    const void* __restrict__ w_hh_raw,     // [6144][2048]
    const void* __restrict__ b_ih_raw,     // [6144]
    const void* __restrict__ b_hh_raw,     // [6144]
    const void* __restrict__ fc2_w_raw,    // [128][2048]
    const void* __restrict__ fc2_b_raw,    // [128]
    void* __restrict__ out_raw,            // [128][25][128]  f32 or bf16
    u16* __restrict__ enc_act,             // [50][128][128] bf16 (fc1 outputs)
    u16* __restrict__ h_b16,               // 2x [128][2048] bf16
    u16* __restrict__ inp_b16,             // 2x [128][128] bf16
    float* __restrict__ inp_f32,           // 2x [128][128] f32
    float* __restrict__ encF_last,         // [128][128] f32 (enc at t=49)
    float* __restrict__ bias_f32,          // 12544 f32
    unsigned* flags, unsigned* gen,
    u16* __restrict__ cv_encx, u16* __restrict__ cv_wih, u16* __restrict__ cv_whh,
    u16* __restrict__ cv_fc2,  u16* __restrict__ cv_fc1)
{
    __shared__ __align__(16) u16 sA[64 * 72];
    __shared__ __align__(16) u16 sB[128 * 72];
    __shared__ int sflag;
    const int wg = blockIdx.x, tid = threadIdx.x;
    const int wgc = wg & 127;               // column-slice id
    const int mrow0 = (wg >> 7) * 64;       // batch-row half
    const int lane = tid & 63, wv = tid >> 6, ar = lane & 15, aq = lane >> 4;
    const int gtid = wg * kNT + tid, gstride = kNB * kNT;
    unsigned tok = 1;

    // ---- phase -1: detect input dtype. bf16 view of f32 data contains Inf/NaN
    // bit patterns in the random low-mantissa halves; genuine bf16 N(0,1) never.
    {
        const u16* p = (const u16*)enc_in_raw;
        int found = 0;
        for (int i = tid; i < 16384; i += kNT) found |= ((p[i] & 0x7F80) == 0x7F80) ? 1 : 0;
        if (tid == 0) sflag = 0;
        __syncthreads();
        if (found) sflag = 1;
        __syncthreads();
    }
    const bool F32 = (sflag != 0);

    // ---- phase 0: weight/bias conversion into ws (f32 path) + bias to f32 ----
    if (F32) {
        cvt_f32_bf16((const float*)w_ih_raw,  cv_wih,  (3 * kR * kD) / 4,      gtid, gstride);
        cvt_f32_bf16((const float*)w_hh_raw,  cv_whh,  (3 * kR * kR) / 4,      gtid, gstride);
        cvt_f32_bf16((const float*)fc2_w_raw, cv_fc2,  (kD * kR) / 4,          gtid, gstride);
        cvt_f32_bf16((const float*)fc1_w_raw, cv_fc1,  (kD * kD) / 4,          gtid, gstride);
        cvt_f32_bf16((const float*)enc_in_raw, cv_encx, (kB * kSin * kD) / 4,  gtid, gstride);
        for (int i = gtid; i < 3 * kR; i += gstride) {
            bias_f32[i]          = ((const float*)b_ih_raw)[i];
            bias_f32[3 * kR + i] = ((const float*)b_hh_raw)[i];
        }
        for (int i = gtid; i < kD; i += gstride) {
            bias_f32[6 * kR + i]      = ((const float*)fc1_b_raw)[i];
            bias_f32[6 * kR + kD + i] = ((const float*)fc2_b_raw)[i];
        }
    } else {
        for (int i = gtid; i < 3 * kR; i += gstride) {
            bias_f32[i]          = bf2f(((const u16*)b_ih_raw)[i]);
            bias_f32[3 * kR + i] = bf2f(((const u16*)b_hh_raw)[i]);
        }
        for (int i = gtid; i < kD; i += gstride) {
            bias_f32[6 * kR + i]      = bf2f(((const u16*)fc1_b_raw)[i]);
            bias_f32[6 * kR + kD + i] = bf2f(((const u16*)fc2_b_raw)[i]);
        }
    }
    // zero h (buffer 0)
    for (int i = gtid; i < kB * kR; i += gstride) h_b16[i] = 0;
    gbar(flags, gen, tok++);

    const u16* ENCX = F32 ? cv_encx : (const u16*)enc_in_raw;
    const u16* WIH  = F32 ? cv_wih  : (const u16*)w_ih_raw;
    const u16* WHH  = F32 ? cv_whh  : (const u16*)w_hh_raw;
    const u16* WF2  = F32 ? cv_fc2  : (const u16*)fc2_w_raw;
    const u16* WF1  = F32 ? cv_fc1  : (const u16*)fc1_w_raw;

    // ---- fc1: enc = x @ fc1_w^T + fc1_b (blocks with wgc<50 handle t=wgc) ----
    if (wgc < kSin) {
        const f32x4 zz = {0.f, 0.f, 0.f, 0.f};
        f32x4 ae[8] = {zz, zz, zz, zz, zz, zz, zz, zz};
        mma_rows64<8>(ENCX + wgc * kD + (size_t)mrow0 * (kSin * kD), kSin * kD,
                      WF1, kD, kD, 0, 16, ae, sA, sB);
#pragma unroll
        for (int j = 0; j < 8; ++j)
#pragma unroll
            for (int r = 0; r < 4; ++r) {
                int m = mrow0 + wv * 16 + aq * 4 + r;
                int col = j * 16 + ar;
                float v = ae[j][r] + bias_f32[6 * kR + col];
                enc_act[((size_t)wgc * kB + m) * kD + col] = f2bf(v);
                if (wgc == kSin - 1) encF_last[(size_t)m * kD + col] = v;
            }
    }
    gbar(flags, gen, tok++);

    // ---- encoder: 49 GRU steps over enc[0..48] ----
    int par = 0;
    for (int t = 0; t < kSin - 1; ++t) {
        gru_step(enc_act + (size_t)t * kB * kD, mrow0, wgc, WIH, WHH, bias_f32,
                 h_b16 + (size_t)par * kB * kR, h_b16 + (size_t)(1 - par) * kB * kR,
                 sA, sB);
        gbar(flags, gen, tok++);
        par ^= 1;
    }

    // ---- decoder: 25 steps, autoregressive; residual chain kept in f32 ----
    const u16*   ib  = enc_act + (size_t)(kSin - 1) * kB * kD;
    const float* ifp = encF_last;
    for (int d = 0; d < kT; ++d) {
        gru_step(ib, mrow0, wgc, WIH, WHH, bias_f32,
                 h_b16 + (size_t)par * kB * kR, h_b16 + (size_t)(1 - par) * kB * kR,
                 sA, sB);
        gbar(flags, gen, tok++);
        par ^= 1;
        // out = inp + h_new @ fc2_w^T + fc2_b   (16 blocks: wgc<8 x two row-halves)
        u16*   nib = inp_b16 + (size_t)(d & 1) * kB * kD;
        float* nif = inp_f32 + (size_t)(d & 1) * kB * kD;
        if (wgc < 8) {
            const f32x4 zz = {0.f, 0.f, 0.f, 0.f};
            f32x4 ao[1] = {zz};
            mma_rows64<1>(h_b16 + (size_t)par * kB * kR + mrow0 * kR, kR,
                          WF2, kR, kR, wgc * 16, 0, ao, sA, sB);
            int col = wgc * 16 + ar;
            float bb = bias_f32[6 * kR + kD + col];
#pragma unroll
            for (int r = 0; r < 4; ++r) {
                int m = mrow0 + wv * 16 + aq * 4 + r;
                float o = ao[0][r] + bb + ifp[(size_t)m * kD + col];
                size_t oidx = ((size_t)m * kT + d) * kD + col;
                if (F32) ((float*)out_raw)[oidx] = o;
                else     ((u16*)out_raw)[oidx]   = f2bf(o);
                nif[(size_t)m * kD + col] = o;
                nib[(size_t)m * kD + col] = f2bf(o);
            }
        }
        gbar(flags, gen, tok++);
        ib = nib; ifp = nif;
    }
}

// ---------------- host launcher ----------------
extern "C" void kernel_launch(void* const* d_in, const int* in_sizes, int n_in,
                              void* d_out, int out_size, void* d_ws, size_t ws_size,
                              hipStream_t stream)
{
    size_t off = 0;
    char* ws = (char*)d_ws;
    auto alloc = [&](size_t bytes) -> char* {
        char* p = ws + off;
        off = (off + bytes + 255) & ~(size_t)255;
        return p;
    };
    // critical (small) buffers first so a small ws still covers the bf16 path
    u16*      enc_act  = (u16*)alloc((size_t)kSin * kB * kD * 2);     // 1.64 MB
    u16*      h_b16    = (u16*)alloc((size_t)2 * kB * kR * 2);        // 1.05 MB
    u16*      inp_b16  = (u16*)alloc((size_t)2 * kB * kD * 2);        // 64 KB
    float*    inp_f32  = (float*)alloc((size_t)2 * kB * kD * 4);      // 128 KB
    float*    encF     = (float*)alloc((size_t)kB * kD * 4);          // 64 KB
    float*    bias_f32 = (float*)alloc((size_t)(6 * kR + 2 * kD) * 4);// 50 KB
    unsigned* flags    = (unsigned*)alloc(kNB * sizeof(unsigned));
    unsigned* gen      = (unsigned*)alloc(256);
    // f32-path conversion buffers (only written when inputs detected as f32)
    u16*      cv_encx  = (u16*)alloc((size_t)kB * kSin * kD * 2);     // 1.64 MB
    u16*      cv_wih   = (u16*)alloc((size_t)3 * kR * kD * 2);        // 1.57 MB
    u16*      cv_whh   = (u16*)alloc((size_t)3 * kR * kR * 2);        // 25.2 MB
    u16*      cv_fc2   = (u16*)alloc((size_t)kD * kR * 2);            // 0.52 MB
    u16*      cv_fc1   = (u16*)alloc((size_t)kD * kD * 2);            // 32 KB
    (void)ws_size; (void)in_sizes; (void)n_in; (void)out_size;

    seq2seq_kernel<<<dim3(kNB), dim3(kNT), 0, stream>>>(
        d_in[0], d_in[2], d_in[3], d_in[4], d_in[5], d_in[6], d_in[7], d_in[8], d_in[9],
        d_out,
        enc_act, h_b16, inp_b16, inp_f32, encF, bias_f32, flags, gen,
        cv_encx, cv_wih, cv_whh, cv_fc2, cv_fc1);
}

// Round 4
// 4226.417 us; speedup vs baseline: 1.0663x; 1.0663x over previous
//
#include <hip/hip_runtime.h>

// ---------------- problem constants ----------------
constexpr int kB   = 128;   // batch
constexpr int kSin = 50;    // encoder seq len
constexpr int kT   = 25;    // decoder steps
constexpr int kD   = 128;   // feature dim
constexpr int kR   = 2048;  // RNN hidden
constexpr int kNB  = 256;   // grid blocks (1 per CU)
constexpr int kNT  = 512;   // threads per block (8 waves, 2/SIMD)

typedef __bf16 bf16x8 __attribute__((ext_vector_type(8)));
typedef float  f32x4  __attribute__((ext_vector_type(4)));
typedef unsigned short u16;

__device__ __forceinline__ float bf2f(u16 u){ union{unsigned i; float f;}x; x.i=((unsigned)u)<<16; return x.f; }
__device__ __forceinline__ u16 f2bf(float f){ union{float f; unsigned i;}x; x.f=f; return (u16)((x.i + 0x7FFFu + ((x.i>>16)&1u))>>16); }
__device__ __forceinline__ float sigm(float x){ return 1.f/(1.f+__expf(-x)); }

// ---- grid barrier: signed flags (0xAA poison < 0), monotone token, >= is skew-safe ----
__device__ __forceinline__ void gbar(int* flags, int k)
{
    __syncthreads();
    if (threadIdx.x == 0)
        __hip_atomic_store(&flags[blockIdx.x], k, __ATOMIC_RELEASE, __HIP_MEMORY_SCOPE_AGENT);
    if (threadIdx.x < 64) {
        const int i0 = (int)threadIdx.x * 4;
        for (;;) {
            int a = __hip_atomic_load(&flags[i0+0], __ATOMIC_RELAXED, __HIP_MEMORY_SCOPE_AGENT);
            int b = __hip_atomic_load(&flags[i0+1], __ATOMIC_RELAXED, __HIP_MEMORY_SCOPE_AGENT);
            int c = __hip_atomic_load(&flags[i0+2], __ATOMIC_RELAXED, __HIP_MEMORY_SCOPE_AGENT);
            int d = __hip_atomic_load(&flags[i0+3], __ATOMIC_RELAXED, __HIP_MEMORY_SCOPE_AGENT);
            if (__ballot((a>=k)&&(b>=k)&&(c>=k)&&(d>=k)) == ~0ull) break;
            __builtin_amdgcn_s_sleep(1);
        }
        __builtin_amdgcn_fence(__ATOMIC_ACQUIRE, "agent");
    }
    __syncthreads();
}

// ---------------- LDS pool (u16 offsets): A0=0, A1=8704, B0=17408, B1=23936 ----------------
// 30464 u16 = 60.9 KB. Row stride 136 elems: ds_read_b128 frags land 2 lanes/bank = free.

typedef u16 u16x4v __attribute__((ext_vector_type(4)));
__device__ __forceinline__ void cvt_f32_bf16(const float* __restrict__ s, u16* __restrict__ d,
                                             int n4, int gtid, int gstride)
{
    for (int i = gtid; i < n4; i += gstride) {
        float4 v = ((const float4*)s)[i];
        u16x4v o = { f2bf(v.x), f2bf(v.y), f2bf(v.z), f2bf(v.w) };
        ((u16x4v*)d)[i] = o;
    }
}

// ---------------- single-iter GEMM (K=128): fc1 (NT=8), fc2 partial (NT=1) ----------------
template<int NT, int NACC>
__device__ __forceinline__ void small_gemm(
    const u16* __restrict__ Am, int alda,   // 64 rows x 128
    const u16* __restrict__ Bp, int bldb,   // NT*16 rows x 128, rows contiguous
    f32x4 (&acc)[NACC], u16* pool)
{
    const int tid=threadIdx.x, lane=tid&63, wv=tid>>6, g=wv>>2, mt=wv&3, ar=lane&15, aq=lane>>4;
    u16* sA = pool;
    u16* sB = pool + 8704;
    { int q=tid,     r=q>>4, c=q&15; *(uint4*)&sA[r*136+c*8] = *(const uint4*)(Am + r*alda + c*8); }
    { int q=tid+512, r=q>>4, c=q&15; *(uint4*)&sA[r*136+c*8] = *(const uint4*)(Am + r*alda + c*8); }
    for (int q=tid; q<NT*256; q+=kNT){
        int r=q>>4, c=q&15;
        *(uint4*)&sB[r*136+c*8] = *(const uint4*)(Bp + (size_t)r*bldb + c*8);
    }
    __syncthreads();
#pragma unroll
    for (int jt=0; jt<NT; ++jt){
        if ((jt&1) != g) continue;
#pragma unroll
        for (int kk=0; kk<4; ++kk){
            bf16x8 a = *(const bf16x8*)&sA[(mt*16+ar)*136 + kk*32 + aq*8];
            bf16x8 b = *(const bf16x8*)&sB[(jt*16+ar)*136 + kk*32 + aq*8];
            acc[jt>>1] = __builtin_amdgcn_mfma_f32_16x16x32_bf16(a,b,acc[jt>>1],0,0,0);
        }
    }
    __syncthreads();
}

// ---------------- pipelined GRU phase ----------------
struct Set { uint4 a0,a1,b0,b1; };

__device__ __forceinline__ void issue_seg(Set& S, const u16* __restrict__ Ab, int alda, int ak0,
                                          const u16* __restrict__ Bw, int bldb, int bk0, int wgc)
{
    const int tid=threadIdx.x;
    { int q=tid,     r=q>>4, c=q&15; S.a0 = *(const uint4*)(Ab + (size_t)r*alda + ak0 + c*8); }
    { int q=tid+512, r=q>>4, c=q&15; S.a1 = *(const uint4*)(Ab + (size_t)r*alda + ak0 + c*8); }
    { int q=tid,     r=q>>4, c=q&15;
      S.b0 = *(const uint4*)(Bw + (size_t)((r>>4)*kR + wgc*16 + (r&15))*bldb + bk0 + c*8); }
    if (tid < 256) { int q=tid+512, r=q>>4, c=q&15;
      S.b1 = *(const uint4*)(Bw + (size_t)((r>>4)*kR + wgc*16 + (r&15))*bldb + bk0 + c*8); }
}

__device__ __forceinline__ void write_seg(const Set& S, u16* sA, u16* sB)
{
    const int tid=threadIdx.x;
    { int q=tid,     r=q>>4, c=q&15; *(uint4*)&sA[r*136+c*8] = S.a0; }
    { int q=tid+512, r=q>>4, c=q&15; *(uint4*)&sA[r*136+c*8] = S.a1; }
    { int q=tid,     r=q>>4, c=q&15; *(uint4*)&sB[r*136+c*8] = S.b0; }
    if (tid<256){ int q=tid+512, r=q>>4, c=q&15; *(uint4*)&sB[r*136+c*8] = S.b1; }
}

// one GRU step: this block computes h'[mrow0..+64][wgc*16..+16]
// waves: group0 (wv<4): r & n gates; group1: z gate. z crosses via LDS zbuf.
__device__ __forceinline__ void gru_phase(
    const u16* __restrict__ hcur,           // [128][2048]
    const u16* __restrict__ xb,             // [128][128] (row stride kD)
    const u16* __restrict__ w_ih, const u16* __restrict__ w_hh,
    const float* __restrict__ bias,
    int wgc, int mrow0,
    u16* __restrict__ hnxt, u16* pool)
{
    const int tid=threadIdx.x, lane=tid&63, wv=tid>>6, g=wv>>2, mt=wv&3, ar=lane&15, aq=lane>>4;
    const u16* hm = hcur + (size_t)mrow0 * kR;
    const u16* xm = xb   + (size_t)mrow0 * kD;
    const f32x4 zz = {0.f,0.f,0.f,0.f};
    f32x4 aR=zz, aN=zz, aXN=zz;     // g0: r(h+x), n_h, n_x ; g1: aR = z(h+x)
    Set S0, S1;
    issue_seg(S0, hm, kR, 0,   w_hh, kR, 0,   wgc);
    issue_seg(S1, hm, kR, 128, w_hh, kR, 128, wgc);
    for (int i=0; i<17; ++i){
        u16* cA = (i&1) ? (pool+8704)  : pool;
        u16* cB = (i&1) ? (pool+23936) : (pool+17408);
        Set& Sc = (i&1) ? S1 : S0;
        write_seg(Sc, cA, cB);
        if (i+2 < 16)       issue_seg(Sc, hm, kR, (i+2)*128, w_hh, kR, (i+2)*128, wgc);
        else if (i+2 == 16) issue_seg(Sc, xm, kD, 0, w_ih, kD, 0, wgc);
        __syncthreads();
        const bool hseg = (i < 16);
#pragma unroll
        for (int kk=0; kk<4; ++kk){
            bf16x8 a = *(const bf16x8*)&cA[(mt*16+ar)*136 + kk*32 + aq*8];
            if (g == 0){
                bf16x8 br = *(const bf16x8*)&cB[ar*136 + kk*32 + aq*8];
                aR = __builtin_amdgcn_mfma_f32_16x16x32_bf16(a,br,aR,0,0,0);
                bf16x8 bn = *(const bf16x8*)&cB[(32+ar)*136 + kk*32 + aq*8];
                if (hseg) aN  = __builtin_amdgcn_mfma_f32_16x16x32_bf16(a,bn,aN,0,0,0);
                else      aXN = __builtin_amdgcn_mfma_f32_16x16x32_bf16(a,bn,aXN,0,0,0);
            } else {
                bf16x8 bz = *(const bf16x8*)&cB[(16+ar)*136 + kk*32 + aq*8];
                aR = __builtin_amdgcn_mfma_f32_16x16x32_bf16(a,bz,aR,0,0,0);
            }
        }
    }
    // epilogue: z exchange via LDS (B1 region free: last read was iter 15, barrier at 16 passed)
    float* zbuf = (float*)(pool + 23936);
    if (g == 1){
#pragma unroll
        for (int rr=0; rr<4; ++rr) zbuf[mt*256 + (aq*4+rr)*16 + ar] = aR[rr];
    }
    __syncthreads();
    if (g == 0){
        const int hc = wgc*16 + ar;
        const float brz = bias[hc]        + bias[3*kR+hc];
        const float bzz = bias[kR+hc]     + bias[4*kR+hc];
        const float bin = bias[2*kR+hc];
        const float bhn = bias[5*kR+hc];
#pragma unroll
        for (int rr=0; rr<4; ++rr){
            int m = mrow0 + mt*16 + aq*4 + rr;   // C/D: row=(lane>>4)*4+reg, col=lane&15
            float r_ = sigm(aR[rr] + brz);
            float z_ = sigm(zbuf[mt*256 + (aq*4+rr)*16 + ar] + bzz);
            float n_ = tanhf(aXN[rr] + bin + r_*(aN[rr] + bhn));
            float hp = bf2f(hcur[(size_t)m*kR + hc]);
            hnxt[(size_t)m*kR + hc] = f2bf((1.f-z_)*n_ + z_*hp);
        }
    }
    __syncthreads();
}

// ---------------- the whole model, one persistent kernel ----------------
__global__ __launch_bounds__(kNT, 2) void seq2seq_kernel(
    const void* __restrict__ enc_in_raw, const void* __restrict__ fc1_w_raw,
    const void* __restrict__ fc1_b_raw,  const void* __restrict__ w_ih_raw,
    const void* __restrict__ w_hh_raw,   const void* __restrict__ b_ih_raw,
    const void* __restrict__ b_hh_raw,   const void* __restrict__ fc2_w_raw,
    const void* __restrict__ fc2_b_raw,
    void* __restrict__ out_raw,
    u16* __restrict__ enc_act,           // [50][128][128] bf16
    u16* __restrict__ h_b16,             // 2x [128][2048] bf16
    u16* __restrict__ inp_b16,           // 2x [128][128] bf16
    float* __restrict__ inp_f32,         // 2x [128][128] f32
    float* __restrict__ encF,            // [128][128] f32
    float* __restrict__ bias,            // 6*kR + 2*kD f32
    float* __restrict__ part,            // 256 x 1024 f32 (fc2 split-K partials)
    int* flags,
    u16* __restrict__ cv_encx, u16* __restrict__ cv_wih, u16* __restrict__ cv_whh,
    u16* __restrict__ cv_fc2,  u16* __restrict__ cv_fc1)
{
    __shared__ __align__(16) u16 pool[30464];
    __shared__ int sflag;
    const int wg = blockIdx.x, tid = threadIdx.x;
    const int wgc = wg & 127, mrow0 = (wg >> 7) * 64;
    const int lane = tid & 63, wv = tid >> 6, g = wv >> 2, mt = wv & 3, ar = lane & 15, aq = lane >> 4;
    const int gtid = wg * kNT + tid, gstride = kNB * kNT;
    int tok = 1;

    // ---- dtype detect: f32-as-bf16 shows Inf/NaN patterns in low halves ----
    {
        const u16* p = (const u16*)enc_in_raw;
        int found = 0;
        for (int i = tid; i < 16384; i += kNT) found |= ((p[i] & 0x7F80) == 0x7F80) ? 1 : 0;
        if (tid == 0) sflag = 0;
        __syncthreads();
        if (found) sflag = 1;
        __syncthreads();
    }
    const bool F32 = (sflag != 0);

    // ---- weight/bias prep + zero h ----
    if (F32) {
        cvt_f32_bf16((const float*)w_ih_raw,  cv_wih,  (3*kR*kD)/4,     gtid, gstride);
        cvt_f32_bf16((const float*)w_hh_raw,  cv_whh,  (3*kR*kR)/4,     gtid, gstride);
        cvt_f32_bf16((const float*)fc2_w_raw, cv_fc2,  (kD*kR)/4,       gtid, gstride);
        cvt_f32_bf16((const float*)fc1_w_raw, cv_fc1,  (kD*kD)/4,       gtid, gstride);
        cvt_f32_bf16((const float*)enc_in_raw,cv_encx, (kB*kSin*kD)/4,  gtid, gstride);
        for (int i = gtid; i < 3*kR; i += gstride) {
            bias[i]        = ((const float*)b_ih_raw)[i];
            bias[3*kR + i] = ((const float*)b_hh_raw)[i];
        }
        for (int i = gtid; i < kD; i += gstride) {
            bias[6*kR + i]      = ((const float*)fc1_b_raw)[i];
            bias[6*kR + kD + i] = ((const float*)fc2_b_raw)[i];
        }
    } else {
        for (int i = gtid; i < 3*kR; i += gstride) {
            bias[i]        = bf2f(((const u16*)b_ih_raw)[i]);
            bias[3*kR + i] = bf2f(((const u16*)b_hh_raw)[i]);
        }
        for (int i = gtid; i < kD; i += gstride) {
            bias[6*kR + i]      = bf2f(((const u16*)fc1_b_raw)[i]);
            bias[6*kR + kD + i] = bf2f(((const u16*)fc2_b_raw)[i]);
        }
    }
    for (int i = gtid; i < kB*kR; i += gstride) h_b16[i] = 0;
    gbar(flags, tok++);

    const u16* ENCX = F32 ? cv_encx : (const u16*)enc_in_raw;
    const u16* WIH  = F32 ? cv_wih  : (const u16*)w_ih_raw;
    const u16* WHH  = F32 ? cv_whh  : (const u16*)w_hh_raw;
    const u16* WF2  = F32 ? cv_fc2  : (const u16*)fc2_w_raw;
    const u16* WF1  = F32 ? cv_fc1  : (const u16*)fc1_w_raw;

    // ---- fc1: blocks with wgc<50 handle t=wgc, 64 rows (mrow0) x 128 cols ----
    if (wgc < kSin) {
        const f32x4 zz = {0.f,0.f,0.f,0.f};
        f32x4 ae[4] = {zz,zz,zz,zz};
        small_gemm<8,4>(ENCX + ((size_t)mrow0*kSin + wgc)*kD, kSin*kD, WF1, kD, ae, pool);
#pragma unroll
        for (int jt=0; jt<8; ++jt){
            if ((jt&1) != g) continue;
            int col = jt*16 + ar;
            float fb = bias[6*kR + col];
#pragma unroll
            for (int rr=0; rr<4; ++rr){
                int m = mrow0 + mt*16 + aq*4 + rr;
                float v = ae[jt>>1][rr] + fb;
                enc_act[((size_t)wgc*kB + m)*kD + col] = f2bf(v);
                if (wgc == kSin-1) encF[(size_t)m*kD + col] = v;
            }
        }
    }
    gbar(flags, tok++);

    // ---- encoder: 49 GRU steps ----
    int par = 0;
    for (int t = 0; t < kSin-1; ++t) {
        gru_phase(h_b16 + (size_t)par*kB*kR, enc_act + (size_t)t*kB*kD,
                  WIH, WHH, bias, wgc, mrow0,
                  h_b16 + (size_t)(1-par)*kB*kR, pool);
        gbar(flags, tok++);
        par ^= 1;
    }

    // ---- decoder: 25 steps ----
    const u16*   ib  = enc_act + (size_t)(kSin-1)*kB*kD;
    const float* ifp = encF;
    for (int d = 0; d < kT; ++d) {
        gru_phase(h_b16 + (size_t)par*kB*kR, ib, WIH, WHH, bias, wgc, mrow0,
                  h_b16 + (size_t)(1-par)*kB*kR, pool);
        gbar(flags, tok++);
        par ^= 1;
        const u16* hnew = h_b16 + (size_t)par*kB*kR;

        // fc2 partials: all 256 blocks; task = (mh=wg>>7, nt=wgc>>4, ks=wgc&15), K=128
        {
            const int nt = wgc >> 4, ks = wgc & 15;
            const f32x4 zz = {0.f,0.f,0.f,0.f};
            f32x4 ao[1] = {zz};
            small_gemm<1,1>(hnew + (size_t)mrow0*kR + ks*128, kR,
                            WF2 + (size_t)(nt*16)*kR + ks*128, kR, ao, pool);
            if (g == 0){
                float* pt = part + (size_t)((((wg>>7)*8 + nt)*16) + ks) * 1024;
#pragma unroll
                for (int rr=0; rr<4; ++rr)
                    pt[(mt*16 + aq*4 + rr)*16 + ar] = ao[0][rr];
            }
        }
        gbar(flags, tok++);

        // reduce: blocks wgc<8 (x2 mh) sum 16 partials, +inp+bias -> out, next inp
        u16*   nib = inp_b16 + (size_t)(d&1)*kB*kD;
        float* nif = inp_f32 + (size_t)(d&1)*kB*kD;
        if (wgc < 8) {
            const int nt = wgc;
            const float* pt = part + (size_t)(((wg>>7)*8 + nt)*16) * 1024;
            for (int e = tid; e < 1024; e += kNT) {
                int Lm = e >> 4, c16 = e & 15;
                int m = mrow0 + Lm, col = nt*16 + c16;
                float s = 0.f;
#pragma unroll
                for (int ks=0; ks<16; ++ks) s += pt[ks*1024 + e];
                float o = s + bias[6*kR + kD + col] + ifp[(size_t)m*kD + col];
                size_t oidx = ((size_t)m*kT + d)*kD + col;
                if (F32) ((float*)out_raw)[oidx] = o;
                else     ((u16*)out_raw)[oidx]   = f2bf(o);
                nif[(size_t)m*kD + col] = o;
                nib[(size_t)m*kD + col] = f2bf(o);
            }
        }
        gbar(flags, tok++);
        ib = nib; ifp = nif;
    }
}

// ---------------- host launcher ----------------
extern "C" void kernel_launch(void* const* d_in, const int* in_sizes, int n_in,
                              void* d_out, int out_size, void* d_ws, size_t ws_size,
                              hipStream_t stream)
{
    size_t off = 0;
    char* ws = (char*)d_ws;
    auto alloc = [&](size_t bytes) -> char* {
        char* p = ws + off;
        off = (off + bytes + 255) & ~(size_t)255;
        return p;
    };
    u16*   enc_act = (u16*)alloc((size_t)kSin*kB*kD*2);
    u16*   h_b16   = (u16*)alloc((size_t)2*kB*kR*2);
    u16*   inp_b16 = (u16*)alloc((size_t)2*kB*kD*2);
    float* inp_f32 = (float*)alloc((size_t)2*kB*kD*4);
    float* encF    = (float*)alloc((size_t)kB*kD*4);
    float* bias    = (float*)alloc((size_t)(6*kR + 2*kD)*4);
    float* part    = (float*)alloc((size_t)256*1024*4);
    int*   flags   = (int*)alloc(kNB*sizeof(int));
    u16*   cv_encx = (u16*)alloc((size_t)kB*kSin*kD*2);
    u16*   cv_wih  = (u16*)alloc((size_t)3*kR*kD*2);
    u16*   cv_whh  = (u16*)alloc((size_t)3*kR*kR*2);
    u16*   cv_fc2  = (u16*)alloc((size_t)kD*kR*2);
    u16*   cv_fc1  = (u16*)alloc((size_t)kD*kD*2);
    (void)ws_size; (void)in_sizes; (void)n_in; (void)out_size;

    seq2seq_kernel<<<dim3(kNB), dim3(kNT), 0, stream>>>(
        d_in[0], d_in[2], d_in[3], d_in[4], d_in[5], d_in[6], d_in[7], d_in[8], d_in[9],
        d_out,
        enc_act, h_b16, inp_b16, inp_f32, encF, bias, part, flags,
        cv_encx, cv_wih, cv_whh, cv_fc2, cv_fc1);
}

// Round 5
// 3941.038 us; speedup vs baseline: 1.1435x; 1.0724x over previous
//
#include <hip/hip_runtime.h>
#include <limits.h>

// ---------------- problem constants ----------------
constexpr int kB   = 128;   // batch
constexpr int kSin = 50;    // encoder seq len
constexpr int kT   = 25;    // decoder steps
constexpr int kD   = 128;   // feature dim
constexpr int kR   = 2048;  // RNN hidden
constexpr int kNB  = 256;   // grid blocks (1 per CU)
constexpr int kNT  = 512;   // threads per block (8 waves, 2/SIMD)

typedef __bf16 bf16x8 __attribute__((ext_vector_type(8)));
typedef float  f32x4  __attribute__((ext_vector_type(4)));
typedef unsigned short u16;

__device__ __forceinline__ float bf2f(u16 u){ union{unsigned i; float f;}x; x.i=((unsigned)u)<<16; return x.f; }
__device__ __forceinline__ u16 f2bf(float f){ union{float f; unsigned i;}x; x.f=f; return (u16)((x.i + 0x7FFFu + ((x.i>>16)&1u))>>16); }
__device__ __forceinline__ float sigm(float x){ return 1.f/(1.f+__expf(-x)); }

// ---- grid barrier v3: ALL barrier traffic is memory-side RMW atomics ----
// Plain atomic loads can be served stale by the poller's own per-XCD L2
// (non-coherent) until eviction (~30 us — measured r3/r4). RMW atomicMax
// executes at the coherence point: always fresh, ~1-2 us visibility.
// flags/gen are poison-safe: 0xAAAAAAAA is negative, tokens are positive,
// atomicMax is monotone; ">= k" is skew-safe.
__device__ __forceinline__ void gbar(int* flags, int* genp, int k)
{
    __syncthreads();
    if (threadIdx.x == 0) {
        __builtin_amdgcn_fence(__ATOMIC_RELEASE, "agent");   // push data (wbl2)
        atomicMax(&flags[blockIdx.x], k);                    // arrival, RMW = visible
    }
    if (blockIdx.x == 0 && threadIdx.x < 64) {
        const int i0 = (int)threadIdx.x * 4;
        for (;;) {
            int a = atomicMax(&flags[i0+0], INT_MIN);        // identity RMW = fresh read
            int b = atomicMax(&flags[i0+1], INT_MIN);
            int c = atomicMax(&flags[i0+2], INT_MIN);
            int d = atomicMax(&flags[i0+3], INT_MIN);
            if (__ballot((a>=k)&&(b>=k)&&(c>=k)&&(d>=k)) == ~0ull) break;
            __builtin_amdgcn_s_sleep(2);
        }
        if (threadIdx.x == 0) atomicMax(genp, k);            // publish
    }
    if (threadIdx.x == 0) {
        while (atomicMax(genp, INT_MIN) < k)                 // identity RMW poll
            __builtin_amdgcn_s_sleep(2);
        __builtin_amdgcn_fence(__ATOMIC_ACQUIRE, "agent");   // invalidate stale L1/L2
    }
    __syncthreads();
}

// ---------------- LDS pool (u16 offsets): A0=0, A1=8704, B0=17408, B1=23936 ----------------
// 30464 u16 = 60.9 KB. Row stride 136 elems: ds_read_b128 frags land 2 lanes/bank = free.

typedef u16 u16x4v __attribute__((ext_vector_type(4)));
__device__ __forceinline__ void cvt_f32_bf16(const float* __restrict__ s, u16* __restrict__ d,
                                             int n4, int gtid, int gstride)
{
    for (int i = gtid; i < n4; i += gstride) {
        float4 v = ((const float4*)s)[i];
        u16x4v o = { f2bf(v.x), f2bf(v.y), f2bf(v.z), f2bf(v.w) };
        ((u16x4v*)d)[i] = o;
    }
}

// ---------------- single-iter GEMM (K=128): fc1 (NT=8), fc2 partial (NT=1) ----------------
template<int NT, int NACC>
__device__ __forceinline__ void small_gemm(
    const u16* __restrict__ Am, int alda,   // 64 rows x 128
    const u16* __restrict__ Bp, int bldb,   // NT*16 rows x 128, rows contiguous
    f32x4 (&acc)[NACC], u16* pool)
{
    const int tid=threadIdx.x, lane=tid&63, wv=tid>>6, g=wv>>2, mt=wv&3, ar=lane&15, aq=lane>>4;
    u16* sA = pool;
    u16* sB = pool + 8704;
    { int q=tid,     r=q>>4, c=q&15; *(uint4*)&sA[r*136+c*8] = *(const uint4*)(Am + r*alda + c*8); }
    { int q=tid+512, r=q>>4, c=q&15; *(uint4*)&sA[r*136+c*8] = *(const uint4*)(Am + r*alda + c*8); }
    for (int q=tid; q<NT*256; q+=kNT){
        int r=q>>4, c=q&15;
        *(uint4*)&sB[r*136+c*8] = *(const uint4*)(Bp + (size_t)r*bldb + c*8);
    }
    __syncthreads();
#pragma unroll
    for (int jt=0; jt<NT; ++jt){
        if ((jt&1) != g) continue;
#pragma unroll
        for (int kk=0; kk<4; ++kk){
            bf16x8 a = *(const bf16x8*)&sA[(mt*16+ar)*136 + kk*32 + aq*8];
            bf16x8 b = *(const bf16x8*)&sB[(jt*16+ar)*136 + kk*32 + aq*8];
            acc[jt>>1] = __builtin_amdgcn_mfma_f32_16x16x32_bf16(a,b,acc[jt>>1],0,0,0);
        }
    }
    __syncthreads();
}

// ---------------- pipelined GRU phase ----------------
struct Set { uint4 a0,a1,b0,b1; };

__device__ __forceinline__ void issue_seg(Set& S, const u16* __restrict__ Ab, int alda, int ak0,
                                          const u16* __restrict__ Bw, int bldb, int bk0, int wgc)
{
    const int tid=threadIdx.x;
    { int q=tid,     r=q>>4, c=q&15; S.a0 = *(const uint4*)(Ab + (size_t)r*alda + ak0 + c*8); }
    { int q=tid+512, r=q>>4, c=q&15; S.a1 = *(const uint4*)(Ab + (size_t)r*alda + ak0 + c*8); }
    { int q=tid,     r=q>>4, c=q&15;
      S.b0 = *(const uint4*)(Bw + (size_t)((r>>4)*kR + wgc*16 + (r&15))*bldb + bk0 + c*8); }
    if (tid < 256) { int q=tid+512, r=q>>4, c=q&15;
      S.b1 = *(const uint4*)(Bw + (size_t)((r>>4)*kR + wgc*16 + (r&15))*bldb + bk0 + c*8); }
}

__device__ __forceinline__ void write_seg(const Set& S, u16* sA, u16* sB)
{
    const int tid=threadIdx.x;
    { int q=tid,     r=q>>4, c=q&15; *(uint4*)&sA[r*136+c*8] = S.a0; }
    { int q=tid+512, r=q>>4, c=q&15; *(uint4*)&sA[r*136+c*8] = S.a1; }
    { int q=tid,     r=q>>4, c=q&15; *(uint4*)&sB[r*136+c*8] = S.b0; }
    if (tid<256){ int q=tid+512, r=q>>4, c=q&15; *(uint4*)&sB[r*136+c*8] = S.b1; }
}

// one GRU step: this block computes h'[mrow0..+64][wgc*16..+16]
// waves: group0 (wv<4): r & n gates; group1: z gate. z crosses via LDS zbuf.
__device__ __forceinline__ void gru_phase(
    const u16* __restrict__ hcur,           // [128][2048]
    const u16* __restrict__ xb,             // [128][128] (row stride kD)
    const u16* __restrict__ w_ih, const u16* __restrict__ w_hh,
    const float* __restrict__ bias,
    int wgc, int mrow0,
    u16* __restrict__ hnxt, u16* pool)
{
    const int tid=threadIdx.x, lane=tid&63, wv=tid>>6, g=wv>>2, mt=wv&3, ar=lane&15, aq=lane>>4;
    const u16* hm = hcur + (size_t)mrow0 * kR;
    const u16* xm = xb   + (size_t)mrow0 * kD;
    const f32x4 zz = {0.f,0.f,0.f,0.f};
    f32x4 aR=zz, aN=zz, aXN=zz;     // g0: r(h+x), n_h, n_x ; g1: aR = z(h+x)
    Set S0, S1;
    issue_seg(S0, hm, kR, 0,   w_hh, kR, 0,   wgc);
    issue_seg(S1, hm, kR, 128, w_hh, kR, 128, wgc);
    for (int i=0; i<17; ++i){
        u16* cA = (i&1) ? (pool+8704)  : pool;
        u16* cB = (i&1) ? (pool+23936) : (pool+17408);
        Set& Sc = (i&1) ? S1 : S0;
        write_seg(Sc, cA, cB);
        if (i+2 < 16)       issue_seg(Sc, hm, kR, (i+2)*128, w_hh, kR, (i+2)*128, wgc);
        else if (i+2 == 16) issue_seg(Sc, xm, kD, 0, w_ih, kD, 0, wgc);
        __syncthreads();
        const bool hseg = (i < 16);
#pragma unroll
        for (int kk=0; kk<4; ++kk){
            bf16x8 a = *(const bf16x8*)&cA[(mt*16+ar)*136 + kk*32 + aq*8];
            if (g == 0){
                bf16x8 br = *(const bf16x8*)&cB[ar*136 + kk*32 + aq*8];
                aR = __builtin_amdgcn_mfma_f32_16x16x32_bf16(a,br,aR,0,0,0);
                bf16x8 bn = *(const bf16x8*)&cB[(32+ar)*136 + kk*32 + aq*8];
                if (hseg) aN  = __builtin_amdgcn_mfma_f32_16x16x32_bf16(a,bn,aN,0,0,0);
                else      aXN = __builtin_amdgcn_mfma_f32_16x16x32_bf16(a,bn,aXN,0,0,0);
            } else {
                bf16x8 bz = *(const bf16x8*)&cB[(16+ar)*136 + kk*32 + aq*8];
                aR = __builtin_amdgcn_mfma_f32_16x16x32_bf16(a,bz,aR,0,0,0);
            }
        }
    }
    // epilogue: z exchange via LDS (B1 region free: last read was iter 15, barrier at 16 passed)
    float* zbuf = (float*)(pool + 23936);
    if (g == 1){
#pragma unroll
        for (int rr=0; rr<4; ++rr) zbuf[mt*256 + (aq*4+rr)*16 + ar] = aR[rr];
    }
    __syncthreads();
    if (g == 0){
        const int hc = wgc*16 + ar;
        const float brz = bias[hc]        + bias[3*kR+hc];
        const float bzz = bias[kR+hc]     + bias[4*kR+hc];
        const float bin = bias[2*kR+hc];
        const float bhn = bias[5*kR+hc];
#pragma unroll
        for (int rr=0; rr<4; ++rr){
            int m = mrow0 + mt*16 + aq*4 + rr;   // C/D: row=(lane>>4)*4+reg, col=lane&15
            float r_ = sigm(aR[rr] + brz);
            float z_ = sigm(zbuf[mt*256 + (aq*4+rr)*16 + ar] + bzz);
            float n_ = tanhf(aXN[rr] + bin + r_*(aN[rr] + bhn));
            float hp = bf2f(hcur[(size_t)m*kR + hc]);
            hnxt[(size_t)m*kR + hc] = f2bf((1.f-z_)*n_ + z_*hp);
        }
    }
    __syncthreads();
}

// ---------------- the whole model, one persistent kernel ----------------
__global__ __launch_bounds__(kNT, 2) void seq2seq_kernel(
    const void* __restrict__ enc_in_raw, const void* __restrict__ fc1_w_raw,
    const void* __restrict__ fc1_b_raw,  const void* __restrict__ w_ih_raw,
    const void* __restrict__ w_hh_raw,   const void* __restrict__ b_ih_raw,
    const void* __restrict__ b_hh_raw,   const void* __restrict__ fc2_w_raw,
    const void* __restrict__ fc2_b_raw,
    void* __restrict__ out_raw,
    u16* __restrict__ enc_act,           // [50][128][128] bf16
    u16* __restrict__ h_b16,             // 2x [128][2048] bf16
    u16* __restrict__ inp_b16,           // 2x [128][128] bf16
    float* __restrict__ inp_f32,         // 2x [128][128] f32
    float* __restrict__ encF,            // [128][128] f32
    float* __restrict__ bias,            // 6*kR + 2*kD f32
    float* __restrict__ part,            // 256 x 1024 f32 (fc2 split-K partials)
    int* flags, int* genp,
    u16* __restrict__ cv_encx, u16* __restrict__ cv_wih, u16* __restrict__ cv_whh,
    u16* __restrict__ cv_fc2,  u16* __restrict__ cv_fc1)
{
    __shared__ __align__(16) u16 pool[30464];
    __shared__ int sflag;
    const int wg = blockIdx.x, tid = threadIdx.x;
    const int wgc = wg & 127, mrow0 = (wg >> 7) * 64;
    const int lane = tid & 63, wv = tid >> 6, g = wv >> 2, mt = wv & 3, ar = lane & 15, aq = lane >> 4;
    const int gtid = wg * kNT + tid, gstride = kNB * kNT;
    int tok = 1;

    // ---- dtype detect: f32-as-bf16 shows Inf/NaN patterns in low halves ----
    {
        const u16* p = (const u16*)enc_in_raw;
        int found = 0;
        for (int i = tid; i < 16384; i += kNT) found |= ((p[i] & 0x7F80) == 0x7F80) ? 1 : 0;
        if (tid == 0) sflag = 0;
        __syncthreads();
        if (found) sflag = 1;
        __syncthreads();
    }
    const bool F32 = (sflag != 0);

    // ---- weight/bias prep + zero h ----
    if (F32) {
        cvt_f32_bf16((const float*)w_ih_raw,  cv_wih,  (3*kR*kD)/4,     gtid, gstride);
        cvt_f32_bf16((const float*)w_hh_raw,  cv_whh,  (3*kR*kR)/4,     gtid, gstride);
        cvt_f32_bf16((const float*)fc2_w_raw, cv_fc2,  (kD*kR)/4,       gtid, gstride);
        cvt_f32_bf16((const float*)fc1_w_raw, cv_fc1,  (kD*kD)/4,       gtid, gstride);
        cvt_f32_bf16((const float*)enc_in_raw,cv_encx, (kB*kSin*kD)/4,  gtid, gstride);
        for (int i = gtid; i < 3*kR; i += gstride) {
            bias[i]        = ((const float*)b_ih_raw)[i];
            bias[3*kR + i] = ((const float*)b_hh_raw)[i];
        }
        for (int i = gtid; i < kD; i += gstride) {
            bias[6*kR + i]      = ((const float*)fc1_b_raw)[i];
            bias[6*kR + kD + i] = ((const float*)fc2_b_raw)[i];
        }
    } else {
        for (int i = gtid; i < 3*kR; i += gstride) {
            bias[i]        = bf2f(((const u16*)b_ih_raw)[i]);
            bias[3*kR + i] = bf2f(((const u16*)b_hh_raw)[i]);
        }
        for (int i = gtid; i < kD; i += gstride) {
            bias[6*kR + i]      = bf2f(((const u16*)fc1_b_raw)[i]);
            bias[6*kR + kD + i] = bf2f(((const u16*)fc2_b_raw)[i]);
        }
    }
    for (int i = gtid; i < kB*kR; i += gstride) h_b16[i] = 0;
    gbar(flags, genp, tok++);

    const u16* ENCX = F32 ? cv_encx : (const u16*)enc_in_raw;
    const u16* WIH  = F32 ? cv_wih  : (const u16*)w_ih_raw;
    const u16* WHH  = F32 ? cv_whh  : (const u16*)w_hh_raw;
    const u16* WF2  = F32 ? cv_fc2  : (const u16*)fc2_w_raw;
    const u16* WF1  = F32 ? cv_fc1  : (const u16*)fc1_w_raw;

    // ---- fc1: blocks with wgc<50 handle t=wgc, 64 rows (mrow0) x 128 cols ----
    if (wgc < kSin) {
        const f32x4 zz = {0.f,0.f,0.f,0.f};
        f32x4 ae[4] = {zz,zz,zz,zz};
        small_gemm<8,4>(ENCX + ((size_t)mrow0*kSin + wgc)*kD, kSin*kD, WF1, kD, ae, pool);
#pragma unroll
        for (int jt=0; jt<8; ++jt){
            if ((jt&1) != g) continue;
            int col = jt*16 + ar;
            float fb = bias[6*kR + col];
#pragma unroll
            for (int rr=0; rr<4; ++rr){
                int m = mrow0 + mt*16 + aq*4 + rr;
                float v = ae[jt>>1][rr] + fb;
                enc_act[((size_t)wgc*kB + m)*kD + col] = f2bf(v);
                if (wgc == kSin-1) encF[(size_t)m*kD + col] = v;
            }
        }
    }
    gbar(flags, genp, tok++);

    // ---- encoder: 49 GRU steps ----
    int par = 0;
    for (int t = 0; t < kSin-1; ++t) {
        gru_phase(h_b16 + (size_t)par*kB*kR, enc_act + (size_t)t*kB*kD,
                  WIH, WHH, bias, wgc, mrow0,
                  h_b16 + (size_t)(1-par)*kB*kR, pool);
        gbar(flags, genp, tok++);
        par ^= 1;
    }

    // ---- decoder: 25 steps ----
    const u16*   ib  = enc_act + (size_t)(kSin-1)*kB*kD;
    const float* ifp = encF;
    for (int d = 0; d < kT; ++d) {
        gru_phase(h_b16 + (size_t)par*kB*kR, ib, WIH, WHH, bias, wgc, mrow0,
                  h_b16 + (size_t)(1-par)*kB*kR, pool);
        gbar(flags, genp, tok++);
        par ^= 1;
        const u16* hnew = h_b16 + (size_t)par*kB*kR;

        // fc2 partials: all 256 blocks; task = (mh=wg>>7, nt=wgc>>4, ks=wgc&15), K=128
        {
            const int nt = wgc >> 4, ks = wgc & 15;
            const f32x4 zz = {0.f,0.f,0.f,0.f};
            f32x4 ao[1] = {zz};
            small_gemm<1,1>(hnew + (size_t)mrow0*kR + ks*128, kR,
                            WF2 + (size_t)(nt*16)*kR + ks*128, kR, ao, pool);
            if (g == 0){
                float* pt = part + (size_t)((((wg>>7)*8 + nt)*16) + ks) * 1024;
#pragma unroll
                for (int rr=0; rr<4; ++rr)
                    pt[(mt*16 + aq*4 + rr)*16 + ar] = ao[0][rr];
            }
        }
        gbar(flags, genp, tok++);

        // reduce: blocks wgc<8 (x2 mh) sum 16 partials, +inp+bias -> out, next inp
        u16*   nib = inp_b16 + (size_t)(d&1)*kB*kD;
        float* nif = inp_f32 + (size_t)(d&1)*kB*kD;
        if (wgc < 8) {
            const int nt = wgc;
            const float* pt = part + (size_t)(((wg>>7)*8 + nt)*16) * 1024;
            for (int e = tid; e < 1024; e += kNT) {
                int Lm = e >> 4, c16 = e & 15;
                int m = mrow0 + Lm, col = nt*16 + c16;
                float s = 0.f;
#pragma unroll
                for (int ks=0; ks<16; ++ks) s += pt[ks*1024 + e];
                float o = s + bias[6*kR + kD + col] + ifp[(size_t)m*kD + col];
                size_t oidx = ((size_t)m*kT + d)*kD + col;
                if (F32) ((float*)out_raw)[oidx] = o;
                else     ((u16*)out_raw)[oidx]   = f2bf(o);
                nif[(size_t)m*kD + col] = o;
                nib[(size_t)m*kD + col] = f2bf(o);
            }
        }
        gbar(flags, genp, tok++);
        ib = nib; ifp = nif;
    }
}

// ---------------- host launcher ----------------
extern "C" void kernel_launch(void* const* d_in, const int* in_sizes, int n_in,
                              void* d_out, int out_size, void* d_ws, size_t ws_size,
                              hipStream_t stream)
{
    size_t off = 0;
    char* ws = (char*)d_ws;
    auto alloc = [&](size_t bytes) -> char* {
        char* p = ws + off;
        off = (off + bytes + 255) & ~(size_t)255;
        return p;
    };
    u16*   enc_act = (u16*)alloc((size_t)kSin*kB*kD*2);
    u16*   h_b16   = (u16*)alloc((size_t)2*kB*kR*2);
    u16*   inp_b16 = (u16*)alloc((size_t)2*kB*kD*2);
    float* inp_f32 = (float*)alloc((size_t)2*kB*kD*4);
    float* encF    = (float*)alloc((size_t)kB*kD*4);
    float* bias    = (float*)alloc((size_t)(6*kR + 2*kD)*4);
    float* part    = (float*)alloc((size_t)256*1024*4);
    int*   flags   = (int*)alloc(kNB*sizeof(int));
    int*   genp    = (int*)alloc(256);
    u16*   cv_encx = (u16*)alloc((size_t)kB*kSin*kD*2);
    u16*   cv_wih  = (u16*)alloc((size_t)3*kR*kD*2);
    u16*   cv_whh  = (u16*)alloc((size_t)3*kR*kR*2);
    u16*   cv_fc2  = (u16*)alloc((size_t)kD*kR*2);
    u16*   cv_fc1  = (u16*)alloc((size_t)kD*kD*2);
    (void)ws_size; (void)in_sizes; (void)n_in; (void)out_size;

    seq2seq_kernel<<<dim3(kNB), dim3(kNT), 0, stream>>>(
        d_in[0], d_in[2], d_in[3], d_in[4], d_in[5], d_in[6], d_in[7], d_in[8], d_in[9],
        d_out,
        enc_act, h_b16, inp_b16, inp_f32, encF, bias, part, flags, genp,
        cv_encx, cv_wih, cv_whh, cv_fc2, cv_fc1);
}

// Round 6
// 1739.968 us; speedup vs baseline: 2.5901x; 2.2650x over previous
//
#include <hip/hip_runtime.h>
#include <limits.h>

// ---------------- problem constants ----------------
constexpr int kB   = 128;   // batch
constexpr int kSin = 50;    // encoder seq len
constexpr int kT   = 25;    // decoder steps
constexpr int kD   = 128;   // feature dim
constexpr int kR   = 2048;  // RNN hidden
constexpr int kNB  = 256;   // grid blocks (1 per CU)
constexpr int kNT  = 512;   // threads per block (8 waves, 2/SIMD)

typedef __bf16 bf16x8 __attribute__((ext_vector_type(8)));
typedef float  f32x4  __attribute__((ext_vector_type(4)));
typedef unsigned short u16;
typedef unsigned long long u64;

__device__ __forceinline__ float bf2f(u16 u){ union{unsigned i; float f;}x; x.i=((unsigned)u)<<16; return x.f; }
__device__ __forceinline__ u16 f2bf(float f){ union{float f; unsigned i;}x; x.f=f; return (u16)((x.i + 0x7FFFu + ((x.i>>16)&1u))>>16); }
__device__ __forceinline__ float sigm(float x){ return 1.f/(1.f+__expf(-x)); }

// coherent (agent-scope, write-through) stores: shared mutable state only.
__device__ __forceinline__ void stg32(unsigned* p, unsigned v){
    __hip_atomic_store(p, v, __ATOMIC_RELAXED, __HIP_MEMORY_SCOPE_AGENT);
}
__device__ __forceinline__ void stg64(u64* p, u64 v){
    __hip_atomic_store(p, v, __ATOMIC_RELAXED, __HIP_MEMORY_SCOPE_AGENT);
}

__device__ __forceinline__ bf16x8 pack8(float4 a, float4 b){
    union{ bf16x8 v; u16 u[8]; } t;
    t.u[0]=f2bf(a.x); t.u[1]=f2bf(a.y); t.u[2]=f2bf(a.z); t.u[3]=f2bf(a.w);
    t.u[4]=f2bf(b.x); t.u[5]=f2bf(b.y); t.u[6]=f2bf(b.z); t.u[7]=f2bf(b.w);
    return t.v;
}

// ---- grid barrier: RMW atomics only; acquire-inv on exit, NO release-wbl2 ----
// __syncthreads() drains vmcnt (coherent stores acked at coherence point) before
// arrival. flags/gen poison-safe: 0xAAAAAAAA<0, tokens>0, atomicMax monotone.
__device__ __forceinline__ void gbar(int* flags, int* genp, int k)
{
    __syncthreads();
    if (threadIdx.x == 0) atomicMax(&flags[blockIdx.x], k);
    if (blockIdx.x == 0 && threadIdx.x < 64) {
        const int i0 = (int)threadIdx.x * 4;
        for (;;) {
            int a = atomicMax(&flags[i0+0], INT_MIN);
            int b = atomicMax(&flags[i0+1], INT_MIN);
            int c = atomicMax(&flags[i0+2], INT_MIN);
            int d = atomicMax(&flags[i0+3], INT_MIN);
            if (__ballot((a>=k)&&(b>=k)&&(c>=k)&&(d>=k)) == ~0ull) break;
            __builtin_amdgcn_s_sleep(2);
        }
        if (threadIdx.x == 0) atomicMax(genp, k);
    }
    if (threadIdx.x == 0) {
        while (atomicMax(genp, INT_MIN) < k) __builtin_amdgcn_s_sleep(2);
        __builtin_amdgcn_fence(__ATOMIC_ACQUIRE, "agent");   // invalidate stale L1/L2
    }
    __syncthreads();
}

__device__ __forceinline__ void cvt_f32_bf16(const float* __restrict__ s, u16* __restrict__ d,
                                             int n4, int gtid, int gstride)
{
    for (int i = gtid; i < n4; i += gstride) {
        float4 v = ((const float4*)s)[i];
        u64 pk = (u64)f2bf(v.x) | ((u64)f2bf(v.y)<<16) | ((u64)f2bf(v.z)<<32) | ((u64)f2bf(v.w)<<48);
        stg64((u64*)d + i, pk);
    }
}

// ---------------- single-iter GEMM (K=128) for fc1 (NT=8) ----------------
template<int NT, int NACC>
__device__ __forceinline__ void small_gemm(
    const u16* __restrict__ Am, int alda,
    const u16* __restrict__ Bp, int bldb,
    f32x4 (&acc)[NACC], u16* pool)
{
    const int tid=threadIdx.x, lane=tid&63, wv=tid>>6, g=wv>>2, mt=wv&3, ar=lane&15, aq=lane>>4;
    u16* sA = pool;
    u16* sB = pool + 8704;
    { int q=tid,     r=q>>4, c=q&15; *(uint4*)&sA[r*136+c*8] = *(const uint4*)(Am + r*alda + c*8); }
    { int q=tid+512, r=q>>4, c=q&15; *(uint4*)&sA[r*136+c*8] = *(const uint4*)(Am + r*alda + c*8); }
    for (int q=tid; q<NT*256; q+=kNT){
        int r=q>>4, c=q&15;
        *(uint4*)&sB[r*136+c*8] = *(const uint4*)(Bp + (size_t)r*bldb + c*8);
    }
    __syncthreads();
#pragma unroll
    for (int jt=0; jt<NT; ++jt){
        if ((jt&1) != g) continue;
#pragma unroll
        for (int kk=0; kk<4; ++kk){
            bf16x8 a = *(const bf16x8*)&sA[(mt*16+ar)*136 + kk*32 + aq*8];
            bf16x8 b = *(const bf16x8*)&sB[(jt*16+ar)*136 + kk*32 + aq*8];
            acc[jt>>1] = __builtin_amdgcn_mfma_f32_16x16x32_bf16(a,b,acc[jt>>1],0,0,0);
        }
    }
    __syncthreads();
}

// ---------------- GRU step with register-resident weights ----------------
// h layout (slice-major): h[s][row][c] = h(row, 16s+c), s<128, row<128, c<16.
// Wave w covers k in [256w, 256w+256). LDS red: cell(w',g4,mt) = f32x4 per lane,
// 4*4*4*64*16B = 64 KB. g4: 0=r, 1=z, 2=n_h, 3=n_x.
__device__ __forceinline__ void gru_phase_reg(
    const u16* __restrict__ hcur, u16* __restrict__ hnxt,
    const u16* __restrict__ xb,
    const bf16x8 (&wB)[3][8], const bf16x8 (&wI)[3],
    const float* __restrict__ bias,
    int wgc, int mrow0, u16* smem)
{
    const int tid=threadIdx.x, lane=tid&63, w=tid>>6, ar=lane&15, aq=lane>>4;
    const f32x4 zz = {0.f,0.f,0.f,0.f};
    f32x4 acc[3][4] = {{zz,zz,zz,zz},{zz,zz,zz,zz},{zz,zz,zz,zz}};
    f32x4 xn[4] = {zz,zz,zz,zz};

#pragma unroll
    for (int mt=0; mt<4; ++mt){
        const int row = mrow0 + mt*16 + ar;
        bf16x8 af[8];
#pragma unroll
        for (int c=0; c<8; ++c){
            const int s = 16*w + 2*c + (aq>>1);
            af[c] = *(const bf16x8*)(hcur + (((s*128 + row)<<4) + (aq&1)*8));
        }
#pragma unroll
        for (int c=0; c<8; ++c){
            acc[0][mt] = __builtin_amdgcn_mfma_f32_16x16x32_bf16(af[c], wB[0][c], acc[0][mt],0,0,0);
            acc[1][mt] = __builtin_amdgcn_mfma_f32_16x16x32_bf16(af[c], wB[1][c], acc[1][mt],0,0,0);
            acc[2][mt] = __builtin_amdgcn_mfma_f32_16x16x32_bf16(af[c], wB[2][c], acc[2][mt],0,0,0);
        }
    }
    if (w < 4){
#pragma unroll
        for (int mt=0; mt<4; ++mt){
            bf16x8 ax = *(const bf16x8*)(xb + (mrow0+mt*16+ar)*kD + 32*w + aq*8);
            acc[0][mt] = __builtin_amdgcn_mfma_f32_16x16x32_bf16(ax, wI[0], acc[0][mt],0,0,0);
            acc[1][mt] = __builtin_amdgcn_mfma_f32_16x16x32_bf16(ax, wI[1], acc[1][mt],0,0,0);
            xn[mt]     = __builtin_amdgcn_mfma_f32_16x16x32_bf16(ax, wI[2], xn[mt],0,0,0);
        }
    }
    float* red = (float*)smem;
#define RCELL(wp,g4,mt) (red + (((((wp)*4+(g4))*4+(mt))*64 + lane)<<2))
    if (w >= 4){
#pragma unroll
        for (int g=0; g<3; ++g)
#pragma unroll
            for (int mt=0; mt<4; ++mt)
                *(f32x4*)RCELL(w-4, g, mt) = acc[g][mt];
    }
    __syncthreads();
    if (w < 4){
#pragma unroll
        for (int g=0; g<3; ++g)
#pragma unroll
            for (int mt=0; mt<4; ++mt)
                acc[g][mt] += *(f32x4*)RCELL(w, g, mt);
#pragma unroll
        for (int g=0; g<3; ++g)
#pragma unroll
            for (int mt=0; mt<4; ++mt)
                *(f32x4*)RCELL(w, g, mt) = acc[g][mt];
#pragma unroll
        for (int mt=0; mt<4; ++mt)
            *(f32x4*)RCELL(w, 3, mt) = xn[mt];
    }
    __syncthreads();
    if (tid < 256){
        const int mt = tid>>6, ls = tid&63, aqs = ls>>4, ars = ls&15;
        f32x4 R=zz, Z=zz, NH=zz, NX=zz;
#pragma unroll
        for (int wp=0; wp<4; ++wp){
            R  += *(f32x4*)(red + ((((wp*4+0)*4+mt)*64 + ls)<<2));
            Z  += *(f32x4*)(red + ((((wp*4+1)*4+mt)*64 + ls)<<2));
            NH += *(f32x4*)(red + ((((wp*4+2)*4+mt)*64 + ls)<<2));
            NX += *(f32x4*)(red + ((((wp*4+3)*4+mt)*64 + ls)<<2));
        }
        const int hc = wgc*16 + ars;
        const float brz = bias[hc]      + bias[3*kR+hc];
        const float bzz = bias[kR+hc]   + bias[4*kR+hc];
        const float bin = bias[2*kR+hc];
        const float bhn = bias[5*kR+hc];
#pragma unroll
        for (int rr=0; rr<4; ++rr){
            const int m = mrow0 + mt*16 + aqs*4 + rr;   // C/D: row=(lane>>4)*4+reg, col=lane&15
            float r_ = sigm(R[rr] + brz);
            float z_ = sigm(Z[rr] + bzz);
            float n_ = tanhf(NX[rr] + bin + r_*(NH[rr] + bhn));
            float hp = bf2f(hcur[((wgc*128 + m)<<4) + ars]);
            u16 hb = f2bf((1.f-z_)*n_ + z_*hp);
            unsigned other = (unsigned)__shfl_xor((int)(unsigned)hb, 1);
            if (!(ars&1))
                stg32((unsigned*)(hnxt + ((wgc*128+m)<<4) + ars), (unsigned)hb | (other<<16));
        }
    }
#undef RCELL
    __syncthreads();
}

// ---------------- fc2 split-K partial (K=128 chunk ks, n-tile nt) ----------------
__device__ __forceinline__ void fc2_gemm(
    const u16* __restrict__ hnew, const u16* __restrict__ WF2,
    int mrow0, int nt, int ks, float* __restrict__ part_tile, u16* smem)
{
    const int tid=threadIdx.x, lane=tid&63, wv=tid>>6, ar=lane&15, aq=lane>>4;
    u16* sA = smem;
    u16* sB = smem + 8704;
#pragma unroll
    for (int rep=0; rep<2; ++rep){
        int q = tid + rep*512, r = q>>4, c = q&15;
        int s = ks*8 + (c>>1), off = (c&1)*8;
        *(uint4*)&sA[r*136+c*8] = *(const uint4*)(hnew + (((s*128 + mrow0 + r)<<4) + off));
    }
    if (tid < 256){
        int r = tid>>4, c = tid&15;
        *(uint4*)&sB[r*136+c*8] = *(const uint4*)(WF2 + (size_t)(nt*16+r)*kR + ks*128 + c*8);
    }
    __syncthreads();
    if (wv < 4){
        const int mt = wv;
        f32x4 ao = {0.f,0.f,0.f,0.f};
#pragma unroll
        for (int kk=0; kk<4; ++kk){
            bf16x8 a = *(const bf16x8*)&sA[(mt*16+ar)*136 + kk*32 + aq*8];
            bf16x8 b = *(const bf16x8*)&sB[ar*136 + kk*32 + aq*8];
            ao = __builtin_amdgcn_mfma_f32_16x16x32_bf16(a,b,ao,0,0,0);
        }
#pragma unroll
        for (int rr=0; rr<4; ++rr)
            stg32((unsigned*)(part_tile + (mt*16 + aq*4 + rr)*16 + ar), __float_as_uint(ao[rr]));
    }
    __syncthreads();
}

// ---------------- the whole model, one persistent kernel ----------------
__global__ __launch_bounds__(kNT, 2) void seq2seq_kernel(
    const void* __restrict__ enc_in_raw, const void* __restrict__ fc1_w_raw,
    const void* __restrict__ fc1_b_raw,  const void* __restrict__ w_ih_raw,
    const void* __restrict__ w_hh_raw,   const void* __restrict__ b_ih_raw,
    const void* __restrict__ b_hh_raw,   const void* __restrict__ fc2_w_raw,
    const void* __restrict__ fc2_b_raw,
    void* __restrict__ out_raw,
    u16* __restrict__ enc_act,           // [50][128][128] bf16
    u16* __restrict__ h_b16,             // 2x slice-major [128][128][16] bf16
    u16* __restrict__ inp_b16,           // 2x [128][128] bf16
    float* __restrict__ inp_f32,         // 2x [128][128] f32
    float* __restrict__ encF,            // [128][128] f32
    float* __restrict__ bias,            // 6*kR + 2*kD f32
    float* __restrict__ part,            // 256 x 1024 f32
    int* flags, int* genp,
    u16* __restrict__ cv_encx, u16* __restrict__ cv_fc2, u16* __restrict__ cv_fc1)
{
    __shared__ __align__(16) u16 smem[32768];   // 64 KB: gru-red / gemm pool (union)
    __shared__ int sflag;
    const int wg = blockIdx.x, tid = threadIdx.x;
    const int wgc = wg & 127, mrow0 = (wg >> 7) * 64;
    const int lane = tid & 63, wv = tid >> 6, ar = lane & 15, aq = lane >> 4;
    const int gtid = wg * kNT + tid, gstride = kNB * kNT;
    int tok = 1;

    // ---- dtype detect: f32-as-bf16 shows Inf/NaN bit patterns in low halves ----
    {
        const u16* p = (const u16*)enc_in_raw;
        int found = 0;
        for (int i = tid; i < 16384; i += kNT) found |= ((p[i] & 0x7F80) == 0x7F80) ? 1 : 0;
        if (tid == 0) sflag = 0;
        __syncthreads();
        if (found) sflag = 1;
        __syncthreads();
    }
    const bool F32 = (sflag != 0);

    // ---- register-resident recurrent weights (persist all 74 steps) ----
    bf16x8 wB[3][8];   // w_hh[gate][k-chunk]: wave wv covers k in [256*wv, +256)
    bf16x8 wI[3];      // w_ih[gate]: wave wv<4 covers k-chunk 32*wv
    {
        const int w4 = wv & 3;
        if (F32){
            const float* Wh = (const float*)w_hh_raw;
            const float* Wi = (const float*)w_ih_raw;
#pragma unroll
            for (int g=0; g<3; ++g)
#pragma unroll
                for (int c=0; c<8; ++c){
                    size_t o = (size_t)(g*kR + wgc*16 + ar)*kR + 256*wv + 32*c + aq*8;
                    wB[g][c] = pack8(*(const float4*)(Wh+o), *(const float4*)(Wh+o+4));
                }
#pragma unroll
            for (int g=0; g<3; ++g){
                size_t o = (size_t)(g*kR + wgc*16 + ar)*kD + 32*w4 + aq*8;
                wI[g] = pack8(*(const float4*)(Wi+o), *(const float4*)(Wi+o+4));
            }
        } else {
            const u16* Wh = (const u16*)w_hh_raw;
            const u16* Wi = (const u16*)w_ih_raw;
#pragma unroll
            for (int g=0; g<3; ++g)
#pragma unroll
                for (int c=0; c<8; ++c)
                    wB[g][c] = *(const bf16x8*)(Wh + (size_t)(g*kR + wgc*16 + ar)*kR + 256*wv + 32*c + aq*8);
#pragma unroll
            for (int g=0; g<3; ++g)
                wI[g] = *(const bf16x8*)(Wi + (size_t)(g*kR + wgc*16 + ar)*kD + 32*w4 + aq*8);
        }
    }

    // ---- init: conversions + bias + zero h, all via coherent stores ----
    if (F32) {
        cvt_f32_bf16((const float*)fc2_w_raw, cv_fc2,  (kD*kR)/4,       gtid, gstride);
        cvt_f32_bf16((const float*)fc1_w_raw, cv_fc1,  (kD*kD)/4,       gtid, gstride);
        cvt_f32_bf16((const float*)enc_in_raw,cv_encx, (kB*kSin*kD)/4,  gtid, gstride);
        for (int i = gtid; i < 3*kR; i += gstride) {
            stg32((unsigned*)&bias[i],        __float_as_uint(((const float*)b_ih_raw)[i]));
            stg32((unsigned*)&bias[3*kR + i], __float_as_uint(((const float*)b_hh_raw)[i]));
        }
        for (int i = gtid; i < kD; i += gstride) {
            stg32((unsigned*)&bias[6*kR + i],      __float_as_uint(((const float*)fc1_b_raw)[i]));
            stg32((unsigned*)&bias[6*kR + kD + i], __float_as_uint(((const float*)fc2_b_raw)[i]));
        }
    } else {
        for (int i = gtid; i < 3*kR; i += gstride) {
            stg32((unsigned*)&bias[i],        __float_as_uint(bf2f(((const u16*)b_ih_raw)[i])));
            stg32((unsigned*)&bias[3*kR + i], __float_as_uint(bf2f(((const u16*)b_hh_raw)[i])));
        }
        for (int i = gtid; i < kD; i += gstride) {
            stg32((unsigned*)&bias[6*kR + i],      __float_as_uint(bf2f(((const u16*)fc1_b_raw)[i])));
            stg32((unsigned*)&bias[6*kR + kD + i], __float_as_uint(bf2f(((const u16*)fc2_b_raw)[i])));
        }
    }
    for (int i = gtid; i < (kB*kR)/2; i += gstride) stg32((unsigned*)h_b16 + i, 0u);
    gbar(flags, genp, tok++);

    const u16* ENCX = F32 ? cv_encx : (const u16*)enc_in_raw;
    const u16* WF2  = F32 ? cv_fc2  : (const u16*)fc2_w_raw;
    const u16* WF1  = F32 ? cv_fc1  : (const u16*)fc1_w_raw;

    // ---- fc1: blocks wgc<50 handle t=wgc ----
    if (wgc < kSin) {
        const int g = wv>>2, mt = wv&3;
        const f32x4 zz = {0.f,0.f,0.f,0.f};
        f32x4 ae[4] = {zz,zz,zz,zz};
        small_gemm<8,4>(ENCX + ((size_t)mrow0*kSin + wgc)*kD, kSin*kD, WF1, kD, ae, smem);
#pragma unroll
        for (int jt=0; jt<8; ++jt){
            if ((jt&1) != g) continue;
            int col = jt*16 + ar;
            float fb = bias[6*kR + col];
#pragma unroll
            for (int rr=0; rr<4; ++rr){
                int m = mrow0 + mt*16 + aq*4 + rr;
                float v = ae[jt>>1][rr] + fb;
                u16 hb = f2bf(v);
                unsigned other = (unsigned)__shfl_xor((int)(unsigned)hb, 1);
                if (!(ar&1))
                    stg32((unsigned*)(enc_act + ((size_t)wgc*kB + m)*kD + col),
                          (unsigned)hb | (other<<16));
                if (wgc == kSin-1)
                    stg32((unsigned*)(encF + (size_t)m*kD + col), __float_as_uint(v));
            }
        }
    }
    gbar(flags, genp, tok++);

    // ---- encoder: 49 GRU steps ----
    int par = 0;
    for (int t = 0; t < kSin-1; ++t) {
        gru_phase_reg(h_b16 + (size_t)par*kB*kR, h_b16 + (size_t)(1-par)*kB*kR,
                      enc_act + (size_t)t*kB*kD, wB, wI, bias, wgc, mrow0, smem);
        gbar(flags, genp, tok++);
        par ^= 1;
    }

    // ---- decoder: 25 steps ----
    const u16*   ib  = enc_act + (size_t)(kSin-1)*kB*kD;
    const float* ifp = encF;
    for (int d = 0; d < kT; ++d) {
        gru_phase_reg(h_b16 + (size_t)par*kB*kR, h_b16 + (size_t)(1-par)*kB*kR,
                      ib, wB, wI, bias, wgc, mrow0, smem);
        gbar(flags, genp, tok++);
        par ^= 1;
        const u16* hnew = h_b16 + (size_t)par*kB*kR;

        // fc2 partials: all 256 blocks; task = (mh, nt=wgc>>4, ks=wgc&15)
        {
            const int nt = wgc >> 4, ks = wgc & 15;
            float* pt = part + (size_t)((((wg>>7)*8 + nt)*16) + ks) * 1024;
            fc2_gemm(hnew, WF2, mrow0, nt, ks, pt, smem);
        }
        gbar(flags, genp, tok++);

        // reduce: blocks wgc<8 sum 16 partials, +inp+bias -> out, next inp
        u16*   nib = inp_b16 + (size_t)(d&1)*kB*kD;
        float* nif = inp_f32 + (size_t)(d&1)*kB*kD;
        if (wgc < 8) {
            const int nt = wgc;
            const float* pt = part + (size_t)(((wg>>7)*8 + nt)*16) * 1024;
            const int e0 = tid*2;
            const int Lm = e0>>4, c0 = e0&15;
            const int m = mrow0 + Lm, col = nt*16 + c0;
            float s0 = 0.f, s1 = 0.f;
#pragma unroll
            for (int ks=0; ks<16; ++ks){ s0 += pt[ks*1024 + e0]; s1 += pt[ks*1024 + e0 + 1]; }
            float o0 = s0 + bias[6*kR + kD + col]     + ifp[(size_t)m*kD + col];
            float o1 = s1 + bias[6*kR + kD + col + 1] + ifp[(size_t)m*kD + col + 1];
            size_t ob = ((size_t)m*kT + d)*kD + col;
            if (F32) { ((float*)out_raw)[ob] = o0; ((float*)out_raw)[ob+1] = o1; }
            else     { ((u16*)out_raw)[ob] = f2bf(o0); ((u16*)out_raw)[ob+1] = f2bf(o1); }
            stg32((unsigned*)(nif + (size_t)m*kD + col),     __float_as_uint(o0));
            stg32((unsigned*)(nif + (size_t)m*kD + col + 1), __float_as_uint(o1));
            stg32((unsigned*)(nib + (size_t)m*kD + col),
                  (unsigned)f2bf(o0) | ((unsigned)f2bf(o1)<<16));
        }
        gbar(flags, genp, tok++);
        ib = nib; ifp = nif;
    }
}

// ---------------- host launcher ----------------
extern "C" void kernel_launch(void* const* d_in, const int* in_sizes, int n_in,
                              void* d_out, int out_size, void* d_ws, size_t ws_size,
                              hipStream_t stream)
{
    size_t off = 0;
    char* ws = (char*)d_ws;
    auto alloc = [&](size_t bytes) -> char* {
        char* p = ws + off;
        off = (off + bytes + 255) & ~(size_t)255;
        return p;
    };
    u16*   enc_act = (u16*)alloc((size_t)kSin*kB*kD*2);
    u16*   h_b16   = (u16*)alloc((size_t)2*kB*kR*2);
    u16*   inp_b16 = (u16*)alloc((size_t)2*kB*kD*2);
    float* inp_f32 = (float*)alloc((size_t)2*kB*kD*4);
    float* encF    = (float*)alloc((size_t)kB*kD*4);
    float* bias    = (float*)alloc((size_t)(6*kR + 2*kD)*4);
    float* part    = (float*)alloc((size_t)256*1024*4);
    int*   flags   = (int*)alloc(kNB*sizeof(int));
    int*   genp    = (int*)alloc(256);
    u16*   cv_encx = (u16*)alloc((size_t)kB*kSin*kD*2);
    u16*   cv_fc2  = (u16*)alloc((size_t)kD*kR*2);
    u16*   cv_fc1  = (u16*)alloc((size_t)kD*kD*2);
    (void)ws_size; (void)in_sizes; (void)n_in; (void)out_size;

    seq2seq_kernel<<<dim3(kNB), dim3(kNT), 0, stream>>>(
        d_in[0], d_in[2], d_in[3], d_in[4], d_in[5], d_in[6], d_in[7], d_in[8], d_in[9],
        d_out,
        enc_act, h_b16, inp_b16, inp_f32, encF, bias, part, flags, genp,
        cv_encx, cv_fc2, cv_fc1);
}

// Round 7
// 1642.947 us; speedup vs baseline: 2.7430x; 1.0591x over previous
//
#include <hip/hip_runtime.h>
#include <limits.h>

// ---------------- problem constants ----------------
constexpr int kB   = 128;   // batch
constexpr int kSin = 50;    // encoder seq len
constexpr int kT   = 25;    // decoder steps
constexpr int kD   = 128;   // feature dim
constexpr int kR   = 2048;  // RNN hidden
constexpr int kNB  = 256;   // grid blocks (1 per CU)
constexpr int kNT  = 512;   // threads per block (8 waves, 2/SIMD)

typedef __bf16 bf16x8 __attribute__((ext_vector_type(8)));
typedef float  f32x4  __attribute__((ext_vector_type(4)));
typedef unsigned short u16;
typedef unsigned long long u64;

__device__ __forceinline__ float bf2f(u16 u){ union{unsigned i; float f;}x; x.i=((unsigned)u)<<16; return x.f; }
__device__ __forceinline__ u16 f2bf(float f){ union{float f; unsigned i;}x; x.f=f; return (u16)((x.i + 0x7FFFu + ((x.i>>16)&1u))>>16); }
__device__ __forceinline__ float sigm(float x){ return 1.f/(1.f+__expf(-x)); }

// coherent (agent-scope, write-through) stores: shared mutable state only.
__device__ __forceinline__ void stg32(unsigned* p, unsigned v){
    __hip_atomic_store(p, v, __ATOMIC_RELAXED, __HIP_MEMORY_SCOPE_AGENT);
}
__device__ __forceinline__ void stg64(u64* p, u64 v){
    __hip_atomic_store(p, v, __ATOMIC_RELAXED, __HIP_MEMORY_SCOPE_AGENT);
}

__device__ __forceinline__ bf16x8 pack8(float4 a, float4 b){
    union{ bf16x8 v; u16 u[8]; } t;
    t.u[0]=f2bf(a.x); t.u[1]=f2bf(a.y); t.u[2]=f2bf(a.z); t.u[3]=f2bf(a.w);
    t.u[4]=f2bf(b.x); t.u[5]=f2bf(b.y); t.u[6]=f2bf(b.z); t.u[7]=f2bf(b.w);
    return t.v;
}

// ---- grid barrier v4: RMW-only + fan-out release ----
// flags: 1 per 64B line (no arrival contention). Release fans out to 64 gen
// lines (parallel RMWs from block0's wave 0); each block polls gen[wg&63]
// -> 4 pollers/line (r6's single genp line serialized 255 pollers = ~8us).
// Poison-safe: 0xAAAAAAAA<0, tokens>0, atomicMax monotone, >=k skew-safe.
__device__ __forceinline__ void gbar(int* flags, int* genp, int k)
{
    __syncthreads();
    const int tid = threadIdx.x, wg = blockIdx.x;
    if (tid == 0) atomicMax(&flags[wg*16], k);
    if (wg == 0 && tid < 64) {
        const int i0 = tid * 4;
        for (;;) {
            int a = atomicMax(&flags[(i0+0)*16], INT_MIN);
            int b = atomicMax(&flags[(i0+1)*16], INT_MIN);
            int c = atomicMax(&flags[(i0+2)*16], INT_MIN);
            int d = atomicMax(&flags[(i0+3)*16], INT_MIN);
            if (__ballot((a>=k)&&(b>=k)&&(c>=k)&&(d>=k)) == ~0ull) break;
            __builtin_amdgcn_s_sleep(1);
        }
        atomicMax(&genp[tid*16], k);
    }
    if (tid == 0) {
        if (wg != 0)
            while (atomicMax(&genp[(wg&63)*16], INT_MIN) < k) __builtin_amdgcn_s_sleep(1);
        __builtin_amdgcn_fence(__ATOMIC_ACQUIRE, "agent");   // invalidate stale L1/L2
    }
    __syncthreads();
}

__device__ __forceinline__ void cvt_f32_bf16(const float* __restrict__ s, u16* __restrict__ d,
                                             int n4, int gtid, int gstride)
{
    for (int i = gtid; i < n4; i += gstride) {
        float4 v = ((const float4*)s)[i];
        u64 pk = (u64)f2bf(v.x) | ((u64)f2bf(v.y)<<16) | ((u64)f2bf(v.z)<<32) | ((u64)f2bf(v.w)<<48);
        stg64((u64*)d + i, pk);
    }
}

// ---------------- single-iter GEMM (K=128) for fc1 (NT=8) ----------------
template<int NT, int NACC>
__device__ __forceinline__ void small_gemm(
    const u16* __restrict__ Am, int alda,
    const u16* __restrict__ Bp, int bldb,
    f32x4 (&acc)[NACC], u16* pool)
{
    const int tid=threadIdx.x, lane=tid&63, wv=tid>>6, g=wv>>2, mt=wv&3, ar=lane&15, aq=lane>>4;
    u16* sA = pool;
    u16* sB = pool + 8704;
    { int q=tid,     r=q>>4, c=q&15; *(uint4*)&sA[r*136+c*8] = *(const uint4*)(Am + r*alda + c*8); }
    { int q=tid+512, r=q>>4, c=q&15; *(uint4*)&sA[r*136+c*8] = *(const uint4*)(Am + r*alda + c*8); }
    for (int q=tid; q<NT*256; q+=kNT){
        int r=q>>4, c=q&15;
        *(uint4*)&sB[r*136+c*8] = *(const uint4*)(Bp + (size_t)r*bldb + c*8);
    }
    __syncthreads();
#pragma unroll
    for (int jt=0; jt<NT; ++jt){
        if ((jt&1) != g) continue;
#pragma unroll
        for (int kk=0; kk<4; ++kk){
            bf16x8 a = *(const bf16x8*)&sA[(mt*16+ar)*136 + kk*32 + aq*8];
            bf16x8 b = *(const bf16x8*)&sB[(jt*16+ar)*136 + kk*32 + aq*8];
            acc[jt>>1] = __builtin_amdgcn_mfma_f32_16x16x32_bf16(a,b,acc[jt>>1],0,0,0);
        }
    }
    __syncthreads();
}

// ---------------- GRU step, register-resident weights ----------------
// h layout (slice-major): h[s][row][c] = h(row, 16s+c). Wave w covers
// k in [256w,+256). LDS red 64 KB. Epilogue also: own-slice h kept in f32
// regs (hprev) and h' bf16 dropped into sH (LDS) for the fused fc2 partial.
__device__ __forceinline__ void gru_phase_reg(
    const u16* __restrict__ hcur, u16* __restrict__ hnxt,
    const u16* __restrict__ xb,
    const bf16x8 (&wB)[3][8], const bf16x8 (&wI)[3],
    const float4 b4, float (&hprev)[4],
    int wgc, int mrow0, u16* smem, u16* sH)
{
    const int tid=threadIdx.x, lane=tid&63, w=tid>>6, ar=lane&15, aq=lane>>4;
    const f32x4 zz = {0.f,0.f,0.f,0.f};
    f32x4 acc[3][4] = {{zz,zz,zz,zz},{zz,zz,zz,zz},{zz,zz,zz,zz}};
    f32x4 xn[4] = {zz,zz,zz,zz};

#pragma unroll
    for (int mt=0; mt<4; ++mt){
        const int row = mrow0 + mt*16 + ar;
        bf16x8 af[8];
#pragma unroll
        for (int c=0; c<8; ++c){
            const int s = 16*w + 2*c + (aq>>1);
            af[c] = *(const bf16x8*)(hcur + (((s*128 + row)<<4) + (aq&1)*8));
        }
#pragma unroll
        for (int c=0; c<8; ++c){
            acc[0][mt] = __builtin_amdgcn_mfma_f32_16x16x32_bf16(af[c], wB[0][c], acc[0][mt],0,0,0);
            acc[1][mt] = __builtin_amdgcn_mfma_f32_16x16x32_bf16(af[c], wB[1][c], acc[1][mt],0,0,0);
            acc[2][mt] = __builtin_amdgcn_mfma_f32_16x16x32_bf16(af[c], wB[2][c], acc[2][mt],0,0,0);
        }
    }
    if (w < 4){
#pragma unroll
        for (int mt=0; mt<4; ++mt){
            bf16x8 ax = *(const bf16x8*)(xb + (mrow0+mt*16+ar)*kD + 32*w + aq*8);
            acc[0][mt] = __builtin_amdgcn_mfma_f32_16x16x32_bf16(ax, wI[0], acc[0][mt],0,0,0);
            acc[1][mt] = __builtin_amdgcn_mfma_f32_16x16x32_bf16(ax, wI[1], acc[1][mt],0,0,0);
            xn[mt]     = __builtin_amdgcn_mfma_f32_16x16x32_bf16(ax, wI[2], xn[mt],0,0,0);
        }
    }
    float* red = (float*)smem;
#define RCELL(wp,g4,mt) (red + (((((wp)*4+(g4))*4+(mt))*64 + lane)<<2))
    if (w >= 4){
#pragma unroll
        for (int g=0; g<3; ++g)
#pragma unroll
            for (int mt=0; mt<4; ++mt)
                *(f32x4*)RCELL(w-4, g, mt) = acc[g][mt];
    }
    __syncthreads();
    if (w < 4){
#pragma unroll
        for (int g=0; g<3; ++g)
#pragma unroll
            for (int mt=0; mt<4; ++mt)
                acc[g][mt] += *(f32x4*)RCELL(w, g, mt);
#pragma unroll
        for (int g=0; g<3; ++g)
#pragma unroll
            for (int mt=0; mt<4; ++mt)
                *(f32x4*)RCELL(w, g, mt) = acc[g][mt];
#pragma unroll
        for (int mt=0; mt<4; ++mt)
            *(f32x4*)RCELL(w, 3, mt) = xn[mt];
    }
    __syncthreads();
    if (tid < 256){
        const int mt = tid>>6, ls = tid&63, aqs = ls>>4, ars = ls&15;
        f32x4 R=zz, Z=zz, NH=zz, NX=zz;
#pragma unroll
        for (int wp=0; wp<4; ++wp){
            R  += *(f32x4*)(red + ((((wp*4+0)*4+mt)*64 + ls)<<2));
            Z  += *(f32x4*)(red + ((((wp*4+1)*4+mt)*64 + ls)<<2));
            NH += *(f32x4*)(red + ((((wp*4+2)*4+mt)*64 + ls)<<2));
            NX += *(f32x4*)(red + ((((wp*4+3)*4+mt)*64 + ls)<<2));
        }
#pragma unroll
        for (int rr=0; rr<4; ++rr){
            const int m = mrow0 + mt*16 + aqs*4 + rr;   // C/D: row=(lane>>4)*4+reg, col=lane&15
            float r_ = sigm(R[rr] + b4.x);
            float z_ = sigm(Z[rr] + b4.y);
            float n_ = tanhf(NX[rr] + b4.z + r_*(NH[rr] + b4.w));
            float hn = (1.f-z_)*n_ + z_*hprev[rr];
            hprev[rr] = hn;
            u16 hb = f2bf(hn);
            sH[(mt*16 + aqs*4 + rr)*16 + ars] = hb;     // LDS for fused fc2 partial
            unsigned other = (unsigned)__shfl_xor((int)(unsigned)hb, 1);
            if (!(ars&1))
                stg32((unsigned*)(hnxt + ((wgc*128+m)<<4) + ars), (unsigned)hb | (other<<16));
        }
    }
#undef RCELL
    __syncthreads();
}

// ---------------- fused fc2 partial: own h'-slice (K=16, zero-padded) ----------------
// part layout: part[mh][row 64][slice 128][col 128] f32
__device__ __forceinline__ void fc2_partial(
    const u16* __restrict__ sH, const bf16x8 (&wF2)[4],
    int wgc, int mh, float* __restrict__ part)
{
    const int tid=threadIdx.x, lane=tid&63, w=tid>>6, ar=lane&15, aq=lane>>4;
    const int mt = w&3, nh = w>>2;
    bf16x8 a;
    if (aq < 2) a = *(const bf16x8*)&sH[(mt*16+ar)*16 + aq*8];
    else {
#pragma unroll
        for (int i=0;i<8;++i) a[i] = (__bf16)0.f;
    }
    const f32x4 zz = {0.f,0.f,0.f,0.f};
    f32x4 acc[4] = {zz,zz,zz,zz};
#pragma unroll
    for (int j=0;j<4;++j)
        acc[j] = __builtin_amdgcn_mfma_f32_16x16x32_bf16(a, wF2[j], acc[j],0,0,0);
#pragma unroll
    for (int j=0;j<4;++j){
        const int col = (nh*4+j)*16 + ar;
#pragma unroll
        for (int rr=0;rr<4;++rr){
            const int row = mt*16 + aq*4 + rr;
            stg32((unsigned*)(part + ((((size_t)mh*64+row)*128 + wgc)*128 + col)),
                  __float_as_uint(acc[j][rr]));
        }
    }
}

// ---------------- the whole model, one persistent kernel ----------------
__global__ __launch_bounds__(kNT, 2) void seq2seq_kernel(
    const void* __restrict__ enc_in_raw, const void* __restrict__ fc1_w_raw,
    const void* __restrict__ fc1_b_raw,  const void* __restrict__ w_ih_raw,
    const void* __restrict__ w_hh_raw,   const void* __restrict__ b_ih_raw,
    const void* __restrict__ b_hh_raw,   const void* __restrict__ fc2_w_raw,
    const void* __restrict__ fc2_b_raw,
    void* __restrict__ out_raw,
    u16* __restrict__ enc_act,           // [50][128][128] bf16
    u16* __restrict__ h_b16,             // 2x slice-major [128][128][16] bf16
    u16* __restrict__ inp_b16,           // 2x [128][128] bf16
    float* __restrict__ inp_f32,         // 2x [128][128] f32
    float* __restrict__ encF,            // [128][128] f32
    float* __restrict__ bias,            // 6*kR + 2*kD f32
    float* __restrict__ part,            // [2][64][128][128] f32 = 8 MB
    int* flags, int* genp,
    u16* __restrict__ cv_encx, u16* __restrict__ cv_fc2, u16* __restrict__ cv_fc1)
{
    __shared__ __align__(16) u16 smem[33792];   // 64 KB red/pool + 2 KB sH
    __shared__ int sflag;
    u16* sH = smem + 32768;
    const int wg = blockIdx.x, tid = threadIdx.x;
    const int wgc = wg & 127, mrow0 = (wg >> 7) * 64;
    const int lane = tid & 63, wv = tid >> 6, ar = lane & 15, aq = lane >> 4;
    const int gtid = wg * kNT + tid, gstride = kNB * kNT;
    int tok = 1;

    // ---- dtype detect: f32-as-bf16 shows Inf/NaN bit patterns in low halves ----
    {
        const u16* p = (const u16*)enc_in_raw;
        int found = 0;
        for (int i = tid; i < 16384; i += kNT) found |= ((p[i] & 0x7F80) == 0x7F80) ? 1 : 0;
        if (tid == 0) sflag = 0;
        __syncthreads();
        if (found) sflag = 1;
        __syncthreads();
    }
    const bool F32 = (sflag != 0);

    // ---- register-resident recurrent weights (persist all 74 steps) ----
    bf16x8 wB[3][8];   // w_hh[gate][k-chunk]: wave wv covers k in [256*wv,+256)
    bf16x8 wI[3];      // w_ih[gate]: wave wv<4 covers k-chunk 32*wv
    {
        const int w4 = wv & 3;
        if (F32){
            const float* Wh = (const float*)w_hh_raw;
            const float* Wi = (const float*)w_ih_raw;
#pragma unroll
            for (int g=0; g<3; ++g)
#pragma unroll
                for (int c=0; c<8; ++c){
                    size_t o = (size_t)(g*kR + wgc*16 + ar)*kR + 256*wv + 32*c + aq*8;
                    wB[g][c] = pack8(*(const float4*)(Wh+o), *(const float4*)(Wh+o+4));
                }
#pragma unroll
            for (int g=0; g<3; ++g){
                size_t o = (size_t)(g*kR + wgc*16 + ar)*kD + 32*w4 + aq*8;
                wI[g] = pack8(*(const float4*)(Wi+o), *(const float4*)(Wi+o+4));
            }
        } else {
            const u16* Wh = (const u16*)w_hh_raw;
            const u16* Wi = (const u16*)w_ih_raw;
#pragma unroll
            for (int g=0; g<3; ++g)
#pragma unroll
                for (int c=0; c<8; ++c)
                    wB[g][c] = *(const bf16x8*)(Wh + (size_t)(g*kR + wgc*16 + ar)*kR + 256*wv + 32*c + aq*8);
#pragma unroll
            for (int g=0; g<3; ++g)
                wI[g] = *(const bf16x8*)(Wi + (size_t)(g*kR + wgc*16 + ar)*kD + 32*w4 + aq*8);
        }
    }

    // ---- init: conversions + bias + zero h, all via coherent stores ----
    if (F32) {
        cvt_f32_bf16((const float*)fc2_w_raw, cv_fc2,  (kD*kR)/4,       gtid, gstride);
        cvt_f32_bf16((const float*)fc1_w_raw, cv_fc1,  (kD*kD)/4,       gtid, gstride);
        cvt_f32_bf16((const float*)enc_in_raw,cv_encx, (kB*kSin*kD)/4,  gtid, gstride);
        for (int i = gtid; i < 3*kR; i += gstride) {
            stg32((unsigned*)&bias[i],        __float_as_uint(((const float*)b_ih_raw)[i]));
            stg32((unsigned*)&bias[3*kR + i], __float_as_uint(((const float*)b_hh_raw)[i]));
        }
        for (int i = gtid; i < kD; i += gstride) {
            stg32((unsigned*)&bias[6*kR + i],      __float_as_uint(((const float*)fc1_b_raw)[i]));
            stg32((unsigned*)&bias[6*kR + kD + i], __float_as_uint(((const float*)fc2_b_raw)[i]));
        }
    } else {
        for (int i = gtid; i < 3*kR; i += gstride) {
            stg32((unsigned*)&bias[i],        __float_as_uint(bf2f(((const u16*)b_ih_raw)[i])));
            stg32((unsigned*)&bias[3*kR + i], __float_as_uint(bf2f(((const u16*)b_hh_raw)[i])));
        }
        for (int i = gtid; i < kD; i += gstride) {
            stg32((unsigned*)&bias[6*kR + i],      __float_as_uint(bf2f(((const u16*)fc1_b_raw)[i])));
            stg32((unsigned*)&bias[6*kR + kD + i], __float_as_uint(bf2f(((const u16*)fc2_b_raw)[i])));
        }
    }
    for (int i = gtid; i < (kB*kR)/2; i += gstride) stg32((unsigned*)h_b16 + i, 0u);
    gbar(flags, genp, tok++);

    const u16* ENCX = F32 ? cv_encx : (const u16*)enc_in_raw;
    const u16* WF2  = F32 ? cv_fc2  : (const u16*)fc2_w_raw;
    const u16* WF1  = F32 ? cv_fc1  : (const u16*)fc1_w_raw;

    // ---- per-thread constant preloads (after gbar: bias/cv visible) ----
    float4 b4;   // gate biases for this thread's (hc)
    {
        const int hc = wgc*16 + ar;
        b4.x = bias[hc]      + bias[3*kR+hc];
        b4.y = bias[kR+hc]   + bias[4*kR+hc];
        b4.z = bias[2*kR+hc];
        b4.w = bias[5*kR+hc];
    }
    bf16x8 wF2[4];   // fc2_w[(nh*4+j)*16+ar][wgc*16 + aq*8 ..+8], reg-resident
    {
        const int nh = wv>>2;
#pragma unroll
        for (int j=0;j<4;++j){
            if (aq < 2)
                wF2[j] = *(const bf16x8*)(WF2 + (size_t)((nh*4+j)*16+ar)*kR + wgc*16 + aq*8);
            else {
#pragma unroll
                for (int i=0;i<8;++i) wF2[j][i] = (__bf16)0.f;
            }
        }
    }
    const float fc2b = bias[6*kR + kD + (wg&1)*64 + (tid&63)];   // for reduce phase
    float hprev[4] = {0.f, 0.f, 0.f, 0.f};                       // own-slice h in f32

    // ---- fc1: blocks wgc<50 handle t=wgc ----
    if (wgc < kSin) {
        const int g = wv>>2, mt = wv&3;
        const f32x4 zz = {0.f,0.f,0.f,0.f};
        f32x4 ae[4] = {zz,zz,zz,zz};
        small_gemm<8,4>(ENCX + ((size_t)mrow0*kSin + wgc)*kD, kSin*kD, WF1, kD, ae, smem);
#pragma unroll
        for (int jt=0; jt<8; ++jt){
            if ((jt&1) != g) continue;
            int col = jt*16 + ar;
            float fb = bias[6*kR + col];
#pragma unroll
            for (int rr=0; rr<4; ++rr){
                int m = mrow0 + mt*16 + aq*4 + rr;
                float v = ae[jt>>1][rr] + fb;
                u16 hb = f2bf(v);
                unsigned other = (unsigned)__shfl_xor((int)(unsigned)hb, 1);
                if (!(ar&1))
                    stg32((unsigned*)(enc_act + ((size_t)wgc*kB + m)*kD + col),
                          (unsigned)hb | (other<<16));
                if (wgc == kSin-1)
                    stg32((unsigned*)(encF + (size_t)m*kD + col), __float_as_uint(v));
            }
        }
    }
    gbar(flags, genp, tok++);

    // ---- encoder: 49 GRU steps ----
    int par = 0;
    for (int t = 0; t < kSin-1; ++t) {
        gru_phase_reg(h_b16 + (size_t)par*kB*kR, h_b16 + (size_t)(1-par)*kB*kR,
                      enc_act + (size_t)t*kB*kD, wB, wI, b4, hprev, wgc, mrow0, smem, sH);
        gbar(flags, genp, tok++);
        par ^= 1;
    }

    // ---- decoder: 25 steps, 2 phases each ----
    const u16*   ib  = enc_act + (size_t)(kSin-1)*kB*kD;
    const float* ifp = encF;
    const int mh = wg >> 7;
    for (int d = 0; d < kT; ++d) {
        // phase A: GRU + own-slice fc2 partial (fused, no extra barrier)
        gru_phase_reg(h_b16 + (size_t)par*kB*kR, h_b16 + (size_t)(1-par)*kB*kR,
                      ib, wB, wI, b4, hprev, wgc, mrow0, smem, sH);
        fc2_partial(sH, wF2, wgc, mh, part);
        gbar(flags, genp, tok++);
        par ^= 1;

        // phase B: reduce 128 slice-partials -> out + next x  (all 256 blocks)
        u16*   nib = inp_b16 + (size_t)(d&1)*kB*kD;
        float* nif = inp_f32 + (size_t)(d&1)*kB*kD;
        {
            const int row = wg >> 1, ch = wg & 1;
            const int mh2 = row >> 6, rl = row & 63;
            const float* pr = part + (size_t)((mh2*64 + rl)*128)*128;
            const int cl = tid & 63, sg = tid >> 6;
            float s = 0.f;
#pragma unroll
            for (int j=0;j<16;++j) s += pr[(size_t)(sg*16+j)*128 + ch*64 + cl];
            float* red2 = (float*)smem;
            red2[sg*64 + cl] = s;
            __syncthreads();
            if (tid < 64){
                float t2 = 0.f;
#pragma unroll
                for (int g2=0; g2<8; ++g2) t2 += red2[g2*64 + tid];
                const int colg = ch*64 + tid;
                const float o = t2 + fc2b + ifp[(size_t)row*kD + colg];
                const size_t ob = ((size_t)row*kT + d)*kD + colg;
                if (F32) ((float*)out_raw)[ob] = o;
                else     ((u16*)out_raw)[ob]   = f2bf(o);
                stg32((unsigned*)(nif + (size_t)row*kD + colg), __float_as_uint(o));
                u16 hb = f2bf(o);
                unsigned other = (unsigned)__shfl_xor((int)(unsigned)hb, 1);
                if (!(tid&1))
                    stg32((unsigned*)(nib + (size_t)row*kD + colg), (unsigned)hb | (other<<16));
            }
        }
        gbar(flags, genp, tok++);
        ib = nib; ifp = nif;
    }
}

// ---------------- host launcher ----------------
extern "C" void kernel_launch(void* const* d_in, const int* in_sizes, int n_in,
                              void* d_out, int out_size, void* d_ws, size_t ws_size,
                              hipStream_t stream)
{
    size_t off = 0;
    char* ws = (char*)d_ws;
    auto alloc = [&](size_t bytes) -> char* {
        char* p = ws + off;
        off = (off + bytes + 255) & ~(size_t)255;
        return p;
    };
    u16*   enc_act = (u16*)alloc((size_t)kSin*kB*kD*2);
    u16*   h_b16   = (u16*)alloc((size_t)2*kB*kR*2);
    u16*   inp_b16 = (u16*)alloc((size_t)2*kB*kD*2);
    float* inp_f32 = (float*)alloc((size_t)2*kB*kD*4);
    float* encF    = (float*)alloc((size_t)kB*kD*4);
    float* bias    = (float*)alloc((size_t)(6*kR + 2*kD)*4);
    float* part    = (float*)alloc((size_t)2*64*128*128*4);      // 8 MB
    int*   flags   = (int*)alloc((size_t)kNB*16*4);              // 1 flag / 64B line
    int*   genp    = (int*)alloc((size_t)64*16*4);               // 64 gen lines
    u16*   cv_encx = (u16*)alloc((size_t)kB*kSin*kD*2);
    u16*   cv_fc2  = (u16*)alloc((size_t)kD*kR*2);
    u16*   cv_fc1  = (u16*)alloc((size_t)kD*kD*2);
    (void)ws_size; (void)in_sizes; (void)n_in; (void)out_size;

    seq2seq_kernel<<<dim3(kNB), dim3(kNT), 0, stream>>>(
        d_in[0], d_in[2], d_in[3], d_in[4], d_in[5], d_in[6], d_in[7], d_in[8], d_in[9],
        d_out,
        enc_act, h_b16, inp_b16, inp_f32, encF, bias, part, flags, genp,
        cv_encx, cv_fc2, cv_fc1);
}

// Round 8
// 1583.301 us; speedup vs baseline: 2.8464x; 1.0377x over previous
//
#include <hip/hip_runtime.h>
#include <limits.h>

// ---------------- problem constants ----------------
constexpr int kB   = 128;   // batch
constexpr int kSin = 50;    // encoder seq len
constexpr int kT   = 25;    // decoder steps
constexpr int kD   = 128;   // feature dim
constexpr int kR   = 2048;  // RNN hidden
constexpr int kNB  = 256;   // grid blocks (1 per CU)
constexpr int kNT  = 512;   // threads per block (8 waves, 2/SIMD)

typedef __bf16 bf16x8 __attribute__((ext_vector_type(8)));
typedef float  f32x4  __attribute__((ext_vector_type(4)));
typedef unsigned short u16;
typedef unsigned long long u64;

__device__ __forceinline__ float bf2f(u16 u){ union{unsigned i; float f;}x; x.i=((unsigned)u)<<16; return x.f; }
__device__ __forceinline__ u16 f2bf(float f){ union{float f; unsigned i;}x; x.f=f; return (u16)((x.i + 0x7FFFu + ((x.i>>16)&1u))>>16); }
__device__ __forceinline__ float sigm(float x){ return 1.f/(1.f+__expf(-x)); }

// ---- coherent access helpers (agent scope) ----
// Stores: relaxed agent atomic = write-through to coherence point (L3).
// Proven by r6/r7: consumers saw data with no release fence anywhere.
// Loads: relaxed agent atomic = bypasses the stale per-XCD L2, reads L3.
// => NO FENCES NEEDED AT ALL (the r7 per-phase acquire-invalidate is gone).
__device__ __forceinline__ void stg32(unsigned* p, unsigned v){
    __hip_atomic_store(p, v, __ATOMIC_RELAXED, __HIP_MEMORY_SCOPE_AGENT);
}
__device__ __forceinline__ void stg64(u64* p, u64 v){
    __hip_atomic_store(p, v, __ATOMIC_RELAXED, __HIP_MEMORY_SCOPE_AGENT);
}
__device__ __forceinline__ unsigned ald32(const void* p){
    return __hip_atomic_load((const unsigned*)p, __ATOMIC_RELAXED, __HIP_MEMORY_SCOPE_AGENT);
}
__device__ __forceinline__ u64 ald64(const void* p){
    return __hip_atomic_load((const u64*)p, __ATOMIC_RELAXED, __HIP_MEMORY_SCOPE_AGENT);
}
__device__ __forceinline__ bf16x8 ald128bf(const u16* p){
    union{ u64 q[2]; bf16x8 v; } t;
    t.q[0] = ald64(p);
    t.q[1] = ald64(p + 4);
    return t.v;
}
__device__ __forceinline__ float aldf(const float* p){
    union{ unsigned u; float f; } t; t.u = ald32(p); return t.f;
}

__device__ __forceinline__ bf16x8 pack8(float4 a, float4 b){
    union{ bf16x8 v; u16 u[8]; } t;
    t.u[0]=f2bf(a.x); t.u[1]=f2bf(a.y); t.u[2]=f2bf(a.z); t.u[3]=f2bf(a.w);
    t.u[4]=f2bf(b.x); t.u[5]=f2bf(b.y); t.u[6]=f2bf(b.z); t.u[7]=f2bf(b.w);
    return t.v;
}

// ---- grid barrier v5: decentralized, fence-free ----
// Arrival: atomicMax (memory-side RMW). Every block scans its domain's flags
// itself with agent atomic loads (fresh; RMW fallback every 32 rounds as
// deadlock insurance). No central publish -> 2 fewer serialized round-trips.
// Domains: after fc1, row-halves are fully independent -> 128-flag domains.
// Poison-safe: 0xAAAAAAAA<0, tokens>0, monotone, >=k skew-safe.
__device__ __forceinline__ void gbar(int* flags, int k, int base, int perlane)
{
    __syncthreads();   // compiler emits s_waitcnt vmcnt(0) before s_barrier:
                       // all agent stores are at the coherence point first.
    const int tid = threadIdx.x;
    if (tid == 0) atomicMax(&flags[blockIdx.x*16], k);
    if (tid < 64) {
        int iter = 0;
        for (;;) {
            bool ok = true;
            for (int j = 0; j < perlane; ++j) {
                const int idx = base + tid*perlane + j;
                int v;
                if ((iter & 31) == 31) v = atomicMax(&flags[idx*16], INT_MIN);
                else                   v = (int)ald32(&flags[idx*16]);
                ok &= (v >= k);
            }
            if (__ballot(ok) == ~0ull) break;
            ++iter;
            __builtin_amdgcn_s_sleep(1);
        }
    }
    __syncthreads();
}

__device__ __forceinline__ void cvt_f32_bf16(const float* __restrict__ s, u16* __restrict__ d,
                                             int n4, int gtid, int gstride)
{
    for (int i = gtid; i < n4; i += gstride) {
        float4 v = ((const float4*)s)[i];
        u64 pk = (u64)f2bf(v.x) | ((u64)f2bf(v.y)<<16) | ((u64)f2bf(v.z)<<32) | ((u64)f2bf(v.w)<<48);
        stg64((u64*)d + i, pk);
    }
}

// ---------------- single-iter GEMM (K=128) for fc1 (NT=8) ----------------
// Inputs here are first-touch read-only (ENCX/WF1 after global barrier):
// plain cached loads are safe.
template<int NT, int NACC>
__device__ __forceinline__ void small_gemm(
    const u16* __restrict__ Am, int alda,
    const u16* __restrict__ Bp, int bldb,
    f32x4 (&acc)[NACC], u16* pool)
{
    const int tid=threadIdx.x, lane=tid&63, wv=tid>>6, g=wv>>2, mt=wv&3, ar=lane&15, aq=lane>>4;
    u16* sA = pool;
    u16* sB = pool + 8704;
    { int q=tid,     r=q>>4, c=q&15; *(uint4*)&sA[r*136+c*8] = *(const uint4*)(Am + r*alda + c*8); }
    { int q=tid+512, r=q>>4, c=q&15; *(uint4*)&sA[r*136+c*8] = *(const uint4*)(Am + r*alda + c*8); }
    for (int q=tid; q<NT*256; q+=kNT){
        int r=q>>4, c=q&15;
        *(uint4*)&sB[r*136+c*8] = *(const uint4*)(Bp + (size_t)r*bldb + c*8);
    }
    __syncthreads();
#pragma unroll
    for (int jt=0; jt<NT; ++jt){
        if ((jt&1) != g) continue;
#pragma unroll
        for (int kk=0; kk<4; ++kk){
            bf16x8 a = *(const bf16x8*)&sA[(mt*16+ar)*136 + kk*32 + aq*8];
            bf16x8 b = *(const bf16x8*)&sB[(jt*16+ar)*136 + kk*32 + aq*8];
            acc[jt>>1] = __builtin_amdgcn_mfma_f32_16x16x32_bf16(a,b,acc[jt>>1],0,0,0);
        }
    }
    __syncthreads();
}

// ---------------- GRU step, register-resident weights ----------------
// h layout (slice-major): h[s][row][c] = h(row, 16s+c). Wave w covers
// k in [256w,+256). All h/x reads are coherent (agent atomic) loads.
__device__ __forceinline__ void gru_phase_reg(
    const u16* __restrict__ hcur, u16* __restrict__ hnxt,
    const u16* __restrict__ xb,
    const bf16x8 (&wB)[3][8], const bf16x8 (&wI)[3],
    const float4 b4, float (&hprev)[4],
    int wgc, int mrow0, u16* smem, u16* sH)
{
    const int tid=threadIdx.x, lane=tid&63, w=tid>>6, ar=lane&15, aq=lane>>4;
    const f32x4 zz = {0.f,0.f,0.f,0.f};
    f32x4 acc[3][4] = {{zz,zz,zz,zz},{zz,zz,zz,zz},{zz,zz,zz,zz}};
    f32x4 xn[4] = {zz,zz,zz,zz};

#pragma unroll
    for (int mt=0; mt<4; ++mt){
        const int row = mrow0 + mt*16 + ar;
        bf16x8 af[8];
#pragma unroll
        for (int c=0; c<8; ++c){
            const int s = 16*w + 2*c + (aq>>1);
            af[c] = ald128bf(hcur + (((s*128 + row)<<4) + (aq&1)*8));
        }
#pragma unroll
        for (int c=0; c<8; ++c){
            acc[0][mt] = __builtin_amdgcn_mfma_f32_16x16x32_bf16(af[c], wB[0][c], acc[0][mt],0,0,0);
            acc[1][mt] = __builtin_amdgcn_mfma_f32_16x16x32_bf16(af[c], wB[1][c], acc[1][mt],0,0,0);
            acc[2][mt] = __builtin_amdgcn_mfma_f32_16x16x32_bf16(af[c], wB[2][c], acc[2][mt],0,0,0);
        }
    }
    if (w < 4){
#pragma unroll
        for (int mt=0; mt<4; ++mt){
            bf16x8 ax = ald128bf(xb + (mrow0+mt*16+ar)*kD + 32*w + aq*8);
            acc[0][mt] = __builtin_amdgcn_mfma_f32_16x16x32_bf16(ax, wI[0], acc[0][mt],0,0,0);
            acc[1][mt] = __builtin_amdgcn_mfma_f32_16x16x32_bf16(ax, wI[1], acc[1][mt],0,0,0);
            xn[mt]     = __builtin_amdgcn_mfma_f32_16x16x32_bf16(ax, wI[2], xn[mt],0,0,0);
        }
    }
    float* red = (float*)smem;
#define RCELL(wp,g4,mt) (red + (((((wp)*4+(g4))*4+(mt))*64 + lane)<<2))
    if (w >= 4){
#pragma unroll
        for (int g=0; g<3; ++g)
#pragma unroll
            for (int mt=0; mt<4; ++mt)
                *(f32x4*)RCELL(w-4, g, mt) = acc[g][mt];
    }
    __syncthreads();
    if (w < 4){
#pragma unroll
        for (int g=0; g<3; ++g)
#pragma unroll
            for (int mt=0; mt<4; ++mt)
                acc[g][mt] += *(f32x4*)RCELL(w, g, mt);
#pragma unroll
        for (int g=0; g<3; ++g)
#pragma unroll
            for (int mt=0; mt<4; ++mt)
                *(f32x4*)RCELL(w, g, mt) = acc[g][mt];
#pragma unroll
        for (int mt=0; mt<4; ++mt)
            *(f32x4*)RCELL(w, 3, mt) = xn[mt];
    }
    __syncthreads();
    if (tid < 256){
        const int mt = tid>>6, ls = tid&63, aqs = ls>>4, ars = ls&15;
        f32x4 R=zz, Z=zz, NH=zz, NX=zz;
#pragma unroll
        for (int wp=0; wp<4; ++wp){
            R  += *(f32x4*)(red + ((((wp*4+0)*4+mt)*64 + ls)<<2));
            Z  += *(f32x4*)(red + ((((wp*4+1)*4+mt)*64 + ls)<<2));
            NH += *(f32x4*)(red + ((((wp*4+2)*4+mt)*64 + ls)<<2));
            NX += *(f32x4*)(red + ((((wp*4+3)*4+mt)*64 + ls)<<2));
        }
#pragma unroll
        for (int rr=0; rr<4; ++rr){
            const int m = mrow0 + mt*16 + aqs*4 + rr;   // C/D: row=(lane>>4)*4+reg, col=lane&15
            float r_ = sigm(R[rr] + b4.x);
            float z_ = sigm(Z[rr] + b4.y);
            float n_ = tanhf(NX[rr] + b4.z + r_*(NH[rr] + b4.w));
            float hn = (1.f-z_)*n_ + z_*hprev[rr];
            hprev[rr] = hn;
            u16 hb = f2bf(hn);
            sH[(mt*16 + aqs*4 + rr)*16 + ars] = hb;     // LDS for fused fc2 partial
            unsigned other = (unsigned)__shfl_xor((int)(unsigned)hb, 1);
            if (!(ars&1))
                stg32((unsigned*)(hnxt + ((wgc*128+m)<<4) + ars), (unsigned)hb | (other<<16));
        }
    }
#undef RCELL
    __syncthreads();
}

// ---------------- fused fc2 partial: own h'-slice (K=16, zero-padded) ----------------
// part layout: part[mh][row 64][slice 128][col 128] f32
__device__ __forceinline__ void fc2_partial(
    const u16* __restrict__ sH, const bf16x8 (&wF2)[4],
    int wgc, int mh, float* __restrict__ part)
{
    const int tid=threadIdx.x, lane=tid&63, w=tid>>6, ar=lane&15, aq=lane>>4;
    const int mt = w&3, nh = w>>2;
    bf16x8 a;
    if (aq < 2) a = *(const bf16x8*)&sH[(mt*16+ar)*16 + aq*8];
    else {
#pragma unroll
        for (int i=0;i<8;++i) a[i] = (__bf16)0.f;
    }
    const f32x4 zz = {0.f,0.f,0.f,0.f};
    f32x4 acc[4] = {zz,zz,zz,zz};
#pragma unroll
    for (int j=0;j<4;++j)
        acc[j] = __builtin_amdgcn_mfma_f32_16x16x32_bf16(a, wF2[j], acc[j],0,0,0);
#pragma unroll
    for (int j=0;j<4;++j){
        const int col = (nh*4+j)*16 + ar;
#pragma unroll
        for (int rr=0;rr<4;++rr){
            const int row = mt*16 + aq*4 + rr;
            stg32((unsigned*)(part + ((((size_t)mh*64+row)*128 + wgc)*128 + col)),
                  __float_as_uint(acc[j][rr]));
        }
    }
}

// ---------------- the whole model, one persistent kernel ----------------
__global__ __launch_bounds__(kNT, 2) void seq2seq_kernel(
    const void* __restrict__ enc_in_raw, const void* __restrict__ fc1_w_raw,
    const void* __restrict__ fc1_b_raw,  const void* __restrict__ w_ih_raw,
    const void* __restrict__ w_hh_raw,   const void* __restrict__ b_ih_raw,
    const void* __restrict__ b_hh_raw,   const void* __restrict__ fc2_w_raw,
    const void* __restrict__ fc2_b_raw,
    void* __restrict__ out_raw,
    u16* __restrict__ enc_act,           // [50][128][128] bf16
    u16* __restrict__ h_b16,             // 2x slice-major [128][128][16] bf16
    u16* __restrict__ inp_b16,           // 2x [128][128] bf16
    float* __restrict__ inp_f32,         // 2x [128][128] f32
    float* __restrict__ encF,            // [128][128] f32
    float* __restrict__ bias,            // 6*kR + 2*kD f32
    float* __restrict__ part,            // [2][64][128][128] f32 = 8 MB
    int* flags,
    u16* __restrict__ cv_encx, u16* __restrict__ cv_fc2, u16* __restrict__ cv_fc1)
{
    __shared__ __align__(16) u16 smem[33792];   // 64 KB red/pool + 2 KB sH
    __shared__ int sflag;
    u16* sH = smem + 32768;
    const int wg = blockIdx.x, tid = threadIdx.x;
    const int wgc = wg & 127, mrow0 = (wg >> 7) * 64;
    const int lane = tid & 63, wv = tid >> 6, ar = lane & 15, aq = lane >> 4;
    const int gtid = wg * kNT + tid, gstride = kNB * kNT;
    const int dom = (wg >> 7) * 128;            // barrier domain base (row half)
    int tok = 1;

    // ---- dtype detect: f32-as-bf16 shows Inf/NaN bit patterns in low halves ----
    {
        const u16* p = (const u16*)enc_in_raw;
        int found = 0;
        for (int i = tid; i < 16384; i += kNT) found |= ((p[i] & 0x7F80) == 0x7F80) ? 1 : 0;
        if (tid == 0) sflag = 0;
        __syncthreads();
        if (found) sflag = 1;
        __syncthreads();
    }
    const bool F32 = (sflag != 0);

    // ---- register-resident recurrent weights (persist all 74 steps) ----
    bf16x8 wB[3][8];   // w_hh[gate][k-chunk]: wave wv covers k in [256*wv,+256)
    bf16x8 wI[3];      // w_ih[gate]: wave wv<4 covers k-chunk 32*wv
    {
        const int w4 = wv & 3;
        if (F32){
            const float* Wh = (const float*)w_hh_raw;
            const float* Wi = (const float*)w_ih_raw;
#pragma unroll
            for (int g=0; g<3; ++g)
#pragma unroll
                for (int c=0; c<8; ++c){
                    size_t o = (size_t)(g*kR + wgc*16 + ar)*kR + 256*wv + 32*c + aq*8;
                    wB[g][c] = pack8(*(const float4*)(Wh+o), *(const float4*)(Wh+o+4));
                }
#pragma unroll
            for (int g=0; g<3; ++g){
                size_t o = (size_t)(g*kR + wgc*16 + ar)*kD + 32*w4 + aq*8;
                wI[g] = pack8(*(const float4*)(Wi+o), *(const float4*)(Wi+o+4));
            }
        } else {
            const u16* Wh = (const u16*)w_hh_raw;
            const u16* Wi = (const u16*)w_ih_raw;
#pragma unroll
            for (int g=0; g<3; ++g)
#pragma unroll
                for (int c=0; c<8; ++c)
                    wB[g][c] = *(const bf16x8*)(Wh + (size_t)(g*kR + wgc*16 + ar)*kR + 256*wv + 32*c + aq*8);
#pragma unroll
            for (int g=0; g<3; ++g)
                wI[g] = *(const bf16x8*)(Wi + (size_t)(g*kR + wgc*16 + ar)*kD + 32*w4 + aq*8);
        }
    }

    // ---- init: conversions + bias + zero h, all via coherent stores ----
    if (F32) {
        cvt_f32_bf16((const float*)fc2_w_raw, cv_fc2,  (kD*kR)/4,       gtid, gstride);
        cvt_f32_bf16((const float*)fc1_w_raw, cv_fc1,  (kD*kD)/4,       gtid, gstride);
        cvt_f32_bf16((const float*)enc_in_raw,cv_encx, (kB*kSin*kD)/4,  gtid, gstride);
        for (int i = gtid; i < 3*kR; i += gstride) {
            stg32((unsigned*)&bias[i],        __float_as_uint(((const float*)b_ih_raw)[i]));
            stg32((unsigned*)&bias[3*kR + i], __float_as_uint(((const float*)b_hh_raw)[i]));
        }
        for (int i = gtid; i < kD; i += gstride) {
            stg32((unsigned*)&bias[6*kR + i],      __float_as_uint(((const float*)fc1_b_raw)[i]));
            stg32((unsigned*)&bias[6*kR + kD + i], __float_as_uint(((const float*)fc2_b_raw)[i]));
        }
    } else {
        for (int i = gtid; i < 3*kR; i += gstride) {
            stg32((unsigned*)&bias[i],        __float_as_uint(bf2f(((const u16*)b_ih_raw)[i])));
            stg32((unsigned*)&bias[3*kR + i], __float_as_uint(bf2f(((const u16*)b_hh_raw)[i])));
        }
        for (int i = gtid; i < kD; i += gstride) {
            stg32((unsigned*)&bias[6*kR + i],      __float_as_uint(bf2f(((const u16*)fc1_b_raw)[i])));
            stg32((unsigned*)&bias[6*kR + kD + i], __float_as_uint(bf2f(((const u16*)fc2_b_raw)[i])));
        }
    }
    for (int i = gtid; i < (kB*kR)/2; i += gstride) stg32((unsigned*)h_b16 + i, 0u);
    gbar(flags, tok++, 0, 4);            // global barrier (256 flags)

    const u16* ENCX = F32 ? cv_encx : (const u16*)enc_in_raw;
    const u16* WF2  = F32 ? cv_fc2  : (const u16*)fc2_w_raw;
    const u16* WF1  = F32 ? cv_fc1  : (const u16*)fc1_w_raw;

    // ---- per-thread constant preloads (first-touch after global barrier) ----
    float4 b4;   // gate biases for this thread's (hc)
    {
        const int hc = wgc*16 + ar;
        b4.x = aldf(&bias[hc])      + aldf(&bias[3*kR+hc]);
        b4.y = aldf(&bias[kR+hc])   + aldf(&bias[4*kR+hc]);
        b4.z = aldf(&bias[2*kR+hc]);
        b4.w = aldf(&bias[5*kR+hc]);
    }
    bf16x8 wF2[4];   // fc2_w[(nh*4+j)*16+ar][wgc*16 + aq*8 ..+8], reg-resident
    {
        const int nh = wv>>2;
#pragma unroll
        for (int j=0;j<4;++j){
            if (aq < 2)
                wF2[j] = ald128bf(WF2 + (size_t)((nh*4+j)*16+ar)*kR + wgc*16 + aq*8);
            else {
#pragma unroll
                for (int i=0;i<8;++i) wF2[j][i] = (__bf16)0.f;
            }
        }
    }
    const float fc2b = aldf(&bias[6*kR + kD + (wg&1)*64 + (tid&63)]);
    float hprev[4] = {0.f, 0.f, 0.f, 0.f};

    // ---- fc1: blocks wgc<50 handle t=wgc ----
    if (wgc < kSin) {
        const int g = wv>>2, mt = wv&3;
        const f32x4 zz = {0.f,0.f,0.f,0.f};
        f32x4 ae[4] = {zz,zz,zz,zz};
        small_gemm<8,4>(ENCX + ((size_t)mrow0*kSin + wgc)*kD, kSin*kD, WF1, kD, ae, smem);
#pragma unroll
        for (int jt=0; jt<8; ++jt){
            if ((jt&1) != g) continue;
            int col = jt*16 + ar;
            float fb = aldf(&bias[6*kR + col]);
#pragma unroll
            for (int rr=0; rr<4; ++rr){
                int m = mrow0 + mt*16 + aq*4 + rr;
                float v = ae[jt>>1][rr] + fb;
                u16 hb = f2bf(v);
                unsigned other = (unsigned)__shfl_xor((int)(unsigned)hb, 1);
                if (!(ar&1))
                    stg32((unsigned*)(enc_act + ((size_t)wgc*kB + m)*kD + col),
                          (unsigned)hb | (other<<16));
                if (wgc == kSin-1)
                    stg32((unsigned*)(encF + (size_t)m*kD + col), __float_as_uint(v));
            }
        }
    }
    gbar(flags, tok++, dom, 2);          // half-domain barrier from here on

    // ---- encoder: 49 GRU steps ----
    int par = 0;
    for (int t = 0; t < kSin-1; ++t) {
        gru_phase_reg(h_b16 + (size_t)par*kB*kR, h_b16 + (size_t)(1-par)*kB*kR,
                      enc_act + (size_t)t*kB*kD, wB, wI, b4, hprev, wgc, mrow0, smem, sH);
        gbar(flags, tok++, dom, 2);
        par ^= 1;
    }

    // ---- decoder: 25 steps, 2 phases each ----
    const u16*   ib  = enc_act + (size_t)(kSin-1)*kB*kD;
    const float* ifp = encF;
    const int mh = wg >> 7;
    for (int d = 0; d < kT; ++d) {
        // phase A: GRU + own-slice fc2 partial (fused)
        gru_phase_reg(h_b16 + (size_t)par*kB*kR, h_b16 + (size_t)(1-par)*kB*kR,
                      ib, wB, wI, b4, hprev, wgc, mrow0, smem, sH);
        fc2_partial(sH, wF2, wgc, mh, part);
        gbar(flags, tok++, dom, 2);
        par ^= 1;

        // phase B: reduce 128 slice-partials -> out + next x
        u16*   nib = inp_b16 + (size_t)(d&1)*kB*kD;
        float* nif = inp_f32 + (size_t)(d&1)*kB*kD;
        {
            const int row = wg >> 1, ch = wg & 1;
            const int mh2 = row >> 6, rl = row & 63;
            const float* pr = part + (size_t)((mh2*64 + rl)*128)*128;
            const int cl = tid & 63, sg = tid >> 6;
            float s = 0.f;
#pragma unroll
            for (int j=0;j<16;++j) s += aldf(&pr[(size_t)(sg*16+j)*128 + ch*64 + cl]);
            float* red2 = (float*)smem;
            red2[sg*64 + cl] = s;
            __syncthreads();
            if (tid < 64){
                float t2 = 0.f;
#pragma unroll
                for (int g2=0; g2<8; ++g2) t2 += red2[g2*64 + tid];
                const int colg = ch*64 + tid;
                const float o = t2 + fc2b + aldf(&ifp[(size_t)row*kD + colg]);
                const size_t ob = ((size_t)row*kT + d)*kD + colg;
                if (F32) ((float*)out_raw)[ob] = o;
                else     ((u16*)out_raw)[ob]   = f2bf(o);
                stg32((unsigned*)(nif + (size_t)row*kD + colg), __float_as_uint(o));
                u16 hb = f2bf(o);
                unsigned other = (unsigned)__shfl_xor((int)(unsigned)hb, 1);
                if (!(tid&1))
                    stg32((unsigned*)(nib + (size_t)row*kD + colg), (unsigned)hb | (other<<16));
            }
        }
        gbar(flags, tok++, dom, 2);
        ib = nib; ifp = nif;
    }
}

// ---------------- host launcher ----------------
extern "C" void kernel_launch(void* const* d_in, const int* in_sizes, int n_in,
                              void* d_out, int out_size, void* d_ws, size_t ws_size,
                              hipStream_t stream)
{
    size_t off = 0;
    char* ws = (char*)d_ws;
    auto alloc = [&](size_t bytes) -> char* {
        char* p = ws + off;
        off = (off + bytes + 255) & ~(size_t)255;
        return p;
    };
    u16*   enc_act = (u16*)alloc((size_t)kSin*kB*kD*2);
    u16*   h_b16   = (u16*)alloc((size_t)2*kB*kR*2);
    u16*   inp_b16 = (u16*)alloc((size_t)2*kB*kD*2);
    float* inp_f32 = (float*)alloc((size_t)2*kB*kD*4);
    float* encF    = (float*)alloc((size_t)kB*kD*4);
    float* bias    = (float*)alloc((size_t)(6*kR + 2*kD)*4);
    float* part    = (float*)alloc((size_t)2*64*128*128*4);      // 8 MB
    int*   flags   = (int*)alloc((size_t)kNB*16*4);              // 1 flag / 64B line
    u16*   cv_encx = (u16*)alloc((size_t)kB*kSin*kD*2);
    u16*   cv_fc2  = (u16*)alloc((size_t)kD*kR*2);
    u16*   cv_fc1  = (u16*)alloc((size_t)kD*kD*2);
    (void)ws_size; (void)in_sizes; (void)n_in; (void)out_size;

    seq2seq_kernel<<<dim3(kNB), dim3(kNT), 0, stream>>>(
        d_in[0], d_in[2], d_in[3], d_in[4], d_in[5], d_in[6], d_in[7], d_in[8], d_in[9],
        d_out,
        enc_act, h_b16, inp_b16, inp_f32, encF, bias, part, flags,
        cv_encx, cv_fc2, cv_fc1);
}